// Round 2
// baseline (1598.394 us; speedup 1.0000x reference)
//
#include <hip/hip_runtime.h>
#include <math.h>

#define T_ 16
#define B_ 512
#define N_ 8192
#define G_ 39
#define ENC_ 128
#define TH_ 64
#define MROWS 8704          // B_ + N_
#define GATE 512            // 4*ENC_
#define KCAT 192            // TH_ + ENC_
#define SCALE_ 0.08838834764831845f
#define LNEPS 1e-5f

__device__ __forceinline__ float sigm(float x){ return 1.0f/(1.0f+expf(-x)); }

// ---------------- prep: build Wcat (512x192), biasg, Wkv (256x128), bkv; zero h0,c ----------
__global__ __launch_bounds__(256) void k_prep(
    const float* __restrict__ Wih, const float* __restrict__ Whh,
    const float* __restrict__ bih, const float* __restrict__ bhh,
    const float* __restrict__ Wk,  const float* __restrict__ bk,
    const float* __restrict__ Wv,  const float* __restrict__ bv,
    float* __restrict__ Wcat, float* __restrict__ biasg,
    float* __restrict__ Wkv,  float* __restrict__ bkv,
    float* __restrict__ Xa,   float* __restrict__ c)
{
  int i = blockIdx.x*256 + threadIdx.x;
  if (i < GATE*KCAT) {
    int n = i / KCAT, k = i % KCAT;
    Wcat[i] = (k < TH_) ? Wih[n*TH_ + k] : Whh[n*ENC_ + (k - TH_)];
  }
  if (i < GATE) biasg[i] = bih[i] + bhh[i];
  if (i < 2*ENC_*ENC_) {
    int n = i >> 7, k = i & 127;
    Wkv[i] = (n < ENC_) ? Wk[n*ENC_ + k] : Wv[(n-ENC_)*ENC_ + k];
  }
  if (i < 2*ENC_) bkv[i] = (i < ENC_) ? bk[i] : bv[i-ENC_];
  if (i < MROWS*ENC_) {
    int m = i >> 7, j = i & 127;
    Xa[m*KCAT + TH_ + j] = 0.0f;   // h0 = 0
    c[i] = 0.0f;                   // c0 = 0
  }
}

// mask element-width helpers: mask is (B*G, ENC) broadcast along ENC.
__device__ __forceinline__ int cellval(const unsigned char* m, long cell, int w) {
  long byte = cell * 128L * w;
  if (w == 1) return m[byte] != 0;
  if (w == 2) return *(const unsigned short*)(m + byte) != 0;
  if (w == 4) return *(const unsigned int*)(m + byte) != 0;
  return *(const unsigned long long*)(m + byte) != 0ULL;
}
// true iff elements j=0..7 of this cell are bit-identical at width w
__device__ __forceinline__ int cellconsist(const unsigned char* m, long cell, int w) {
  long byte = cell * 128L * w;
  if (w == 1) { unsigned char v = m[byte];
    for (int j = 1; j < 8; ++j) if (m[byte + j] != v) return 0; return 1; }
  if (w == 2) { unsigned short v = *(const unsigned short*)(m + byte);
    for (int j = 1; j < 8; ++j) if (*(const unsigned short*)(m + byte + 2L*j) != v) return 0; return 1; }
  if (w == 4) { unsigned int v = *(const unsigned int*)(m + byte);
    for (int j = 1; j < 8; ++j) if (*(const unsigned int*)(m + byte + 4L*j) != v) return 0; return 1; }
  unsigned long long v = *(const unsigned long long*)(m + byte);
  for (int j = 1; j < 8; ++j) if (*(const unsigned long long*)(m + byte + 8L*j) != v) return 0; return 1;
}

// ---------------- neighbor index scan with mask-width autodetect ----------
// nidx[b*G+g] = rank among true cells, or -1
__global__ void k_scan(const unsigned char* __restrict__ mask, int* __restrict__ nidx)
{
  __shared__ int cnt[256];
  __shared__ int okflag;
  __shared__ int chosen;
  const int CH = (B_*G_) / 256;      // 78, exact
  int tid = threadIdx.x;
  int base = tid * CH;

  if (tid == 0) chosen = 0;
  __syncthreads();

  // detect element width: smallest w whose first 4992 cells (in-bounds for
  // every candidate width tried before a larger one) are broadcast-uniform.
  // Widths tested ascending; a larger width is only probed after all smaller
  // ones failed, which implies the buffer really is that large.
  const int DCH = 4992 / 256;        // 19.5 -> use 4992 = 256*19.5; do 20 with clamp
  for (int w = 1; w <= 8; w <<= 1) {
    if (chosen) break;               // uniform decision (shared, post-barrier)
    int ok = 1;
    for (int j = 0; j < DCH + 1; ++j) {
      long cell = (long)tid * (DCH + 1) + j;
      if (cell < 4992) ok &= cellconsist(mask, cell, w);
    }
    if (tid == 0) okflag = 1;
    __syncthreads();
    if (!ok) okflag = 0;             // benign race, any-writer
    __syncthreads();
    if (tid == 0 && okflag) chosen = w;
    __syncthreads();
  }
  int w = chosen ? chosen : 1;

  int c = 0;
  for (int j = 0; j < CH; ++j) c += cellval(mask, base + j, w);
  cnt[tid] = c;
  __syncthreads();
  for (int off = 1; off < 256; off <<= 1) {
    int v = (tid >= off) ? cnt[tid - off] : 0;
    __syncthreads();
    cnt[tid] += v;
    __syncthreads();
  }
  int run = cnt[tid] - c;            // exclusive prefix
  for (int j = 0; j < CH; ++j) {
    int on = cellval(mask, base + j, w);
    nidx[base + j] = on ? run : -1;
    run += on;
  }
}

// ---------------- per-t input encoder: elu(in5 @ W1^T + b1) -> X enc columns ----------
__global__ __launch_bounds__(256) void k_encode(int t,
    const float* __restrict__ hist, const float* __restrict__ cls, const float* __restrict__ va,
    const float* __restrict__ nbrs, const float* __restrict__ nbrscls, const float* __restrict__ nbrsva,
    const float* __restrict__ W1, const float* __restrict__ b1, float* __restrict__ Xcur)
{
  int i = blockIdx.x*256 + threadIdx.x;
  if (i >= MROWS*TH_) return;
  int o = i & 63, m = i >> 6;
  float in0, in1, in2, in3, in4;
  if (m < B_) {
    int r = t*B_ + m;
    in0 = hist[r*2]; in1 = hist[r*2+1]; in2 = cls[r]; in3 = va[r*2]; in4 = va[r*2+1];
  } else {
    int r = t*N_ + (m - B_);
    in0 = nbrs[r*2]; in1 = nbrs[r*2+1]; in2 = nbrscls[r]; in3 = nbrsva[r*2]; in4 = nbrsva[r*2+1];
  }
  const float* w = W1 + o*5;
  float s = b1[o] + in0*w[0] + in1*w[1] + in2*w[2] + in3*w[3] + in4*w[4];
  Xcur[(long)m*KCAT + o] = (s > 0.0f) ? s : expm1f(s);
}

// ---------------- generic fp32 GEMM: C[M,N] = A[M,K](lda) @ W^T (W is (N,K) ldw) + bias ------
// tiles 64x64, BK=32, 256 threads, 4x4 microtile. M%64==0, N%64==0, K%32==0.
__global__ __launch_bounds__(256) void k_gemm(
    const float* __restrict__ A, int lda,
    const float* __restrict__ W, int ldw,
    const float* __restrict__ bias,
    float* __restrict__ C, int ldc, int K)
{
  __shared__ float As[32][68];
  __shared__ float Bs[32][68];
  const int bm = blockIdx.x * 64;
  const int bn = blockIdx.y * 64;
  const int tid = threadIdx.x;
  const int tx = tid & 15, ty = tid >> 4;
  float acc[4][4] = {};
  for (int k0 = 0; k0 < K; k0 += 32) {
    #pragma unroll
    for (int l = 0; l < 8; ++l) {
      int idx = tid + l*256;
      int r = idx >> 5, kk = idx & 31;
      As[kk][r] = A[(long)(bm + r)*lda + (k0 + kk)];
      Bs[kk][r] = W[(long)(bn + r)*ldw + (k0 + kk)];
    }
    __syncthreads();
    #pragma unroll
    for (int kk = 0; kk < 32; ++kk) {
      float a0 = As[kk][ty*4+0], a1 = As[kk][ty*4+1],
            a2 = As[kk][ty*4+2], a3 = As[kk][ty*4+3];
      float b0 = Bs[kk][tx*4+0], b1 = Bs[kk][tx*4+1],
            b2 = Bs[kk][tx*4+2], b3 = Bs[kk][tx*4+3];
      acc[0][0] += a0*b0; acc[0][1] += a0*b1; acc[0][2] += a0*b2; acc[0][3] += a0*b3;
      acc[1][0] += a1*b0; acc[1][1] += a1*b1; acc[1][2] += a1*b2; acc[1][3] += a1*b3;
      acc[2][0] += a2*b0; acc[2][1] += a2*b1; acc[2][2] += a2*b2; acc[2][3] += a2*b3;
      acc[3][0] += a3*b0; acc[3][1] += a3*b1; acc[3][2] += a3*b2; acc[3][3] += a3*b3;
    }
    __syncthreads();
  }
  const int cc = bn + tx*4;
  float bb0 = bias[cc], bb1 = bias[cc+1], bb2 = bias[cc+2], bb3 = bias[cc+3];
  #pragma unroll
  for (int i2 = 0; i2 < 4; ++i2) {
    long r = bm + ty*4 + i2;
    float4 o;
    o.x = acc[i2][0] + bb0;
    o.y = acc[i2][1] + bb1;
    o.z = acc[i2][2] + bb2;
    o.w = acc[i2][3] + bb3;
    *reinterpret_cast<float4*>(C + r*ldc + cc) = o;
  }
}

// ---------------- LSTM cell update; writes h into Xnext, hist rows also into hh ----------
__global__ __launch_bounds__(256) void k_cell(int t,
    const float* __restrict__ g, float* __restrict__ c,
    float* __restrict__ Xnext, float* __restrict__ hh)
{
  int i = blockIdx.x*256 + threadIdx.x;
  if (i >= MROWS*ENC_) return;
  int m = i >> 7, j = i & 127;
  const float* gr = g + (long)m*GATE;
  float gi = gr[j], gf = gr[ENC_ + j], gg = gr[2*ENC_ + j], go = gr[3*ENC_ + j];
  float cc = sigm(gf)*c[i] + sigm(gi)*tanhf(gg);
  c[i] = cc;
  float hv = sigm(go)*tanhf(cc);
  Xnext[(long)m*KCAT + TH_ + j] = hv;
  if (m < B_) hh[((long)m*T_ + t)*ENC_ + j] = hv;   // hist_hidden (B,T,128)
}

// ---------------- spatial attention for one t: block per b, 128 threads ----------
__global__ __launch_bounds__(128) void k_attn_sp(
    const float* __restrict__ q, int t,
    const float* __restrict__ knv,           // (N,256): k | v
    const float* __restrict__ bk, const float* __restrict__ bv,
    const int* __restrict__ nidx, float* __restrict__ spa)
{
  int b = blockIdx.x;
  int tid = threadIdx.x;              // 128 = 4 heads x 32
  int h2 = tid >> 5, d = tid & 31;
  __shared__ float aw[4][40];
  __shared__ int sn[G_];
  if (tid < G_) sn[tid] = nidx[b*G_ + tid];
  __syncthreads();
  float qv = q[((long)b*T_ + t)*ENC_ + tid];
  for (int g = 0; g < G_; ++g) {
    int ni = sn[g];
    float kv = (ni >= 0) ? knv[(long)ni*256 + tid] : bk[tid];
    float pp = qv * kv;
    pp += __shfl_xor(pp, 16); pp += __shfl_xor(pp, 8);
    pp += __shfl_xor(pp, 4);  pp += __shfl_xor(pp, 2); pp += __shfl_xor(pp, 1);
    if (d == 0) aw[h2][g] = pp * SCALE_;
  }
  __syncthreads();
  float mx = -1e30f;
  for (int g = d; g < G_; g += 32) mx = fmaxf(mx, aw[h2][g]);
  for (int off = 16; off; off >>= 1) mx = fmaxf(mx, __shfl_xor(mx, off));
  float sum = 0.0f;
  for (int g = d; g < G_; g += 32) { float e = expf(aw[h2][g] - mx); aw[h2][g] = e; sum += e; }
  for (int off = 16; off; off >>= 1) sum += __shfl_xor(sum, off);
  float inv = 1.0f / sum;
  __syncthreads();
  float acc = 0.0f;
  for (int g = 0; g < G_; ++g) {
    int ni = sn[g];
    float vv = (ni >= 0) ? knv[(long)ni*256 + 128 + tid] : bv[tid];
    acc += aw[h2][g] * vv;
  }
  spa[((long)b*T_ + t)*ENC_ + tid] = acc * inv;
}

// ---------------- GLU elementwise: out = a * sigmoid(g) ----------
__global__ __launch_bounds__(256) void k_glumul(
    const float* __restrict__ a, const float* __restrict__ g, float* __restrict__ o, int n)
{
  int i = blockIdx.x*256 + threadIdx.x;
  if (i < n) o[i] = a[i] * sigm(g[i]);
}

// ---------------- fused add + layernorm; one wave per 128-ch row ----------
__global__ __launch_bounds__(256) void k_addln(
    const float* __restrict__ A, const float* __restrict__ Bv,
    const float* __restrict__ g, const float* __restrict__ bb,
    float* __restrict__ sum_out, float* __restrict__ ln_out, int rows)
{
  int gtid = blockIdx.x*256 + threadIdx.x;
  int w = gtid >> 6;
  int lane = threadIdx.x & 63;
  if (w >= rows) return;
  long base = (long)w*ENC_;
  float x0 = A[base + lane]      + Bv[base + lane];
  float x1 = A[base + 64 + lane] + Bv[base + 64 + lane];
  if (sum_out) { sum_out[base + lane] = x0; sum_out[base + 64 + lane] = x1; }
  float s = x0 + x1, s2 = x0*x0 + x1*x1;
  for (int off = 32; off; off >>= 1) { s += __shfl_xor(s, off); s2 += __shfl_xor(s2, off); }
  float mean = s * (1.0f/128.0f);
  float var  = s2 * (1.0f/128.0f) - mean*mean;
  float inv  = rsqrtf(var + LNEPS);
  ln_out[base + lane]      = (x0 - mean)*inv*g[lane]      + bb[lane];
  ln_out[base + 64 + lane] = (x1 - mean)*inv*g[64 + lane] + bb[64 + lane];
}

// ---------------- temporal attention: block per b, 128 threads ----------
__global__ __launch_bounds__(128) void k_attn_t(
    const float* __restrict__ qt, const float* __restrict__ kt,
    const float* __restrict__ vt, float* __restrict__ out)
{
  int b = blockIdx.x, tid = threadIdx.x;
  __shared__ float sq[16][128], sk[16][128], sv[16][128];
  __shared__ float sc[16][4][16];     // [t][h][s]
  for (int i = tid; i < T_*ENC_; i += 128) {
    int tt = i >> 7, j = i & 127;
    long a = ((long)b*T_ + tt)*ENC_ + j;
    sq[tt][j] = qt[a]; sk[tt][j] = kt[a]; sv[tt][j] = vt[a];
  }
  __syncthreads();
  for (int e = tid; e < 1024; e += 128) {
    int t = e >> 6, s = (e >> 2) & 15, h2 = e & 3;
    float pp = 0.0f;
    #pragma unroll
    for (int d2 = 0; d2 < 32; ++d2) pp += sq[t][h2*32 + d2] * sk[s][h2*32 + d2];
    sc[t][h2][s] = pp * SCALE_;
  }
  __syncthreads();
  if (tid < 64) {
    int t = tid >> 2, h2 = tid & 3;
    float mx = -1e30f;
    for (int s = 0; s < 16; ++s) mx = fmaxf(mx, sc[t][h2][s]);
    float sum = 0.0f;
    for (int s = 0; s < 16; ++s) { float e2 = expf(sc[t][h2][s] - mx); sc[t][h2][s] = e2; sum += e2; }
    float inv = 1.0f / sum;
    for (int s = 0; s < 16; ++s) sc[t][h2][s] *= inv;
  }
  __syncthreads();
  int h2 = tid >> 5, d2 = tid & 31;
  for (int t = 0; t < 16; ++t) {
    float acc = 0.0f;
    for (int s = 0; s < 16; ++s) acc += sc[t][h2][s] * sv[s][h2*32 + d2];
    out[((long)b*T_ + t)*ENC_ + tid] = acc;
  }
}

extern "C" void kernel_launch(void* const* d_in, const int* in_sizes, int n_in,
                              void* d_out, int out_size, void* d_ws, size_t ws_size,
                              hipStream_t stream)
{
  const float* hist    = (const float*)d_in[0];
  const float* nbrs    = (const float*)d_in[1];
  const float* va      = (const float*)d_in[2];
  const float* nbrsva  = (const float*)d_in[3];
  const float* cls     = (const float*)d_in[6];
  const float* nbrscls = (const float*)d_in[7];
  const unsigned char* mask = (const unsigned char*)d_in[8];
  const float* W1  = (const float*)d_in[9];
  const float* b1  = (const float*)d_in[10];
  const float* Wih = (const float*)d_in[11];
  const float* Whh = (const float*)d_in[12];
  const float* bih = (const float*)d_in[13];
  const float* bhh = (const float*)d_in[14];
  const float* Wq  = (const float*)d_in[15];
  const float* bq  = (const float*)d_in[16];
  const float* Wk  = (const float*)d_in[17];
  const float* bk  = (const float*)d_in[18];
  const float* Wv  = (const float*)d_in[19];
  const float* bv  = (const float*)d_in[20];
  const float* Wg1a = (const float*)d_in[21];
  const float* bg1a = (const float*)d_in[22];
  const float* Wg1g = (const float*)d_in[23];
  const float* bg1g = (const float*)d_in[24];
  const float* Wqt = (const float*)d_in[25];
  const float* bqt = (const float*)d_in[26];
  const float* Wkt = (const float*)d_in[27];
  const float* bkt = (const float*)d_in[28];
  const float* Wvt = (const float*)d_in[29];
  const float* bvt = (const float*)d_in[30];
  const float* Wg2a = (const float*)d_in[31];
  const float* bg2a = (const float*)d_in[32];
  const float* Wg2g = (const float*)d_in[33];
  const float* bg2g = (const float*)d_in[34];
  const float* ln_g = (const float*)d_in[35];
  const float* ln_b = (const float*)d_in[36];

  // workspace layout (floats)
  float* p = (float*)d_ws;
  float* Wcat  = p; p += GATE*KCAT;          // 98304
  float* biasg = p; p += GATE;
  float* Wkv   = p; p += 2*ENC_*ENC_;        // 32768
  float* bkv   = p; p += 2*ENC_;
  float* Xa    = p; p += (long)MROWS*KCAT;   // 1,671,168
  float* Xb    = p; p += (long)MROWS*KCAT;
  float* cbuf  = p; p += (long)MROWS*ENC_;   // 1,114,112
  float* gbuf  = p; p += (long)MROWS*GATE;   // 4,456,448
  float* hh    = p; p += (long)B_*T_*ENC_;   // 1,048,576
  float* knv   = p; p += (long)N_*2*ENC_;    // 2,097,152
  float* q     = p; p += (long)B_*T_*ENC_;
  float* spa   = p; p += (long)B_*T_*ENC_;
  float* t1    = p; p += (long)B_*T_*ENC_;
  float* t2    = p; p += (long)B_*T_*ENC_;
  float* spaG  = p; p += (long)B_*T_*ENC_;
  float* S1    = p; p += (long)B_*T_*ENC_;
  float* vals  = p; p += (long)B_*T_*ENC_;
  float* qt    = p; p += (long)B_*T_*ENC_;
  float* kt    = p; p += (long)B_*T_*ENC_;
  float* vt    = p; p += (long)B_*T_*ENC_;
  float* ato   = p; p += (long)B_*T_*ENC_;
  float* tG2   = p; p += (long)B_*T_*ENC_;
  int*   nidx  = (int*)p;                    // 19,968 ints

  const int ROWS = B_*T_;                    // 8192
  const int NELT = ROWS*ENC_;                // 1,048,576

  k_prep<<<(MROWS*ENC_ + 255)/256, 256, 0, stream>>>(
      Wih, Whh, bih, bhh, Wk, bk, Wv, bv, Wcat, biasg, Wkv, bkv, Xa, cbuf);
  k_scan<<<1, 256, 0, stream>>>(mask, nidx);

  float* Xcur = Xa;
  float* Xnxt = Xb;
  for (int t = 0; t < T_; ++t) {
    k_encode<<<(MROWS*TH_ + 255)/256, 256, 0, stream>>>(
        t, hist, cls, va, nbrs, nbrscls, nbrsva, W1, b1, Xcur);
    k_gemm<<<dim3(MROWS/64, GATE/64), 256, 0, stream>>>(
        Xcur, KCAT, Wcat, KCAT, biasg, gbuf, GATE, KCAT);
    k_cell<<<(MROWS*ENC_ + 255)/256, 256, 0, stream>>>(t, gbuf, cbuf, Xnxt, hh);
    // k|v for this t's neighbors: A = h rows of Xnxt (nbr part)
    const float* nh = Xnxt + (long)B_*KCAT + TH_;
    k_gemm<<<dim3(N_/64, (2*ENC_)/64), 256, 0, stream>>>(
        nh, KCAT, Wkv, ENC_, bkv, knv, 2*ENC_, ENC_);
    // q for this t: A = hist h rows of Xnxt; C strided into q (B,T,128)
    k_gemm<<<dim3(B_/64, ENC_/64), 256, 0, stream>>>(
        Xnxt + TH_, KCAT, Wq, ENC_, bq, q + (long)t*ENC_, T_*ENC_, ENC_);
    k_attn_sp<<<B_, 128, 0, stream>>>(q, t, knv, bk, bv, nidx, spa);
    float* tmp = Xcur; Xcur = Xnxt; Xnxt = tmp;
  }

  // GLU1 on spa
  k_gemm<<<dim3(ROWS/64, ENC_/64), 256, 0, stream>>>(spa, ENC_, Wg1a, ENC_, bg1a, t1, ENC_, ENC_);
  k_gemm<<<dim3(ROWS/64, ENC_/64), 256, 0, stream>>>(spa, ENC_, Wg1g, ENC_, bg1g, t2, ENC_, ENC_);
  k_glumul<<<(NELT + 255)/256, 256, 0, stream>>>(t1, t2, spaG, NELT);
  // values = LN(hh + spaG), keep S1 = hh + spaG
  k_addln<<<(ROWS*64 + 255)/256, 256, 0, stream>>>(hh, spaG, ln_g, ln_b, S1, vals, ROWS);
  // temporal qkv
  k_gemm<<<dim3(ROWS/64, ENC_/64), 256, 0, stream>>>(vals, ENC_, Wqt, ENC_, bqt, qt, ENC_, ENC_);
  k_gemm<<<dim3(ROWS/64, ENC_/64), 256, 0, stream>>>(vals, ENC_, Wkt, ENC_, bkt, kt, ENC_, ENC_);
  k_gemm<<<dim3(ROWS/64, ENC_/64), 256, 0, stream>>>(vals, ENC_, Wvt, ENC_, bvt, vt, ENC_, ENC_);
  k_attn_t<<<B_, 128, 0, stream>>>(qt, kt, vt, ato);
  // GLU2
  k_gemm<<<dim3(ROWS/64, ENC_/64), 256, 0, stream>>>(ato, ENC_, Wg2a, ENC_, bg2a, t1, ENC_, ENC_);
  k_gemm<<<dim3(ROWS/64, ENC_/64), 256, 0, stream>>>(ato, ENC_, Wg2g, ENC_, bg2g, t2, ENC_, ENC_);
  k_glumul<<<(NELT + 255)/256, 256, 0, stream>>>(t1, t2, tG2, NELT);
  // out = LN(S1 + tG2)
  k_addln<<<(ROWS*64 + 255)/256, 256, 0, stream>>>(S1, tG2, ln_g, ln_b, nullptr, (float*)d_out, ROWS);
}

// Round 3
// 900.474 us; speedup vs baseline: 1.7751x; 1.7751x over previous
//
#include <hip/hip_runtime.h>
#include <math.h>

#define T_ 16
#define B_ 512
#define N_ 8192
#define G_ 39
#define ENC_ 128
#define TH_ 64
#define MROWS 8704          // B_ + N_
#define GATE 512            // 4*ENC_
#define KCAT 192            // TH_ + ENC_
#define SCALE_ 0.08838834764831845f
#define LNEPS 1e-5f

typedef short bf16x8 __attribute__((ext_vector_type(8)));
typedef float f32x4  __attribute__((ext_vector_type(4)));

__device__ __forceinline__ float sigm(float x){ return 1.0f/(1.0f+expf(-x)); }
__device__ __forceinline__ unsigned short f2bf(float f){
  unsigned int u = __float_as_uint(f);
  unsigned int r = u + 0x7FFFu + ((u>>16)&1u);
  return (unsigned short)(r>>16);
}
__device__ __forceinline__ float bf2f(unsigned short h){
  return __uint_as_float(((unsigned int)h)<<16);
}

// ================= prep: convert weights to bf16, build fused biases, zero state ======
__global__ __launch_bounds__(256) void k_prep(
    const float* __restrict__ Wih, const float* __restrict__ Whh,
    const float* __restrict__ bih, const float* __restrict__ bhh,
    const float* __restrict__ Wk,  const float* __restrict__ bk,
    const float* __restrict__ Wv,  const float* __restrict__ bv,
    const float* __restrict__ Wq,
    const float* __restrict__ Wqt, const float* __restrict__ bqt,
    const float* __restrict__ Wkt, const float* __restrict__ bkt,
    const float* __restrict__ Wvt, const float* __restrict__ bvt,
    const float* __restrict__ Wg1a, const float* __restrict__ bg1a,
    const float* __restrict__ Wg1g, const float* __restrict__ bg1g,
    const float* __restrict__ Wg2a, const float* __restrict__ bg2a,
    const float* __restrict__ Wg2g, const float* __restrict__ bg2g,
    unsigned short* __restrict__ WcatB, float* __restrict__ biasg,
    unsigned short* __restrict__ WkvB,  float* __restrict__ bkv,
    unsigned short* __restrict__ WqB,
    unsigned short* __restrict__ WqktB, float* __restrict__ bqkt,
    unsigned short* __restrict__ Wg1B,  float* __restrict__ bg1,
    unsigned short* __restrict__ Wg2B,  float* __restrict__ bg2,
    unsigned short* __restrict__ Ha, float* __restrict__ cbuf)
{
  int i = blockIdx.x*256 + threadIdx.x;
  if (i < GATE*KCAT) {
    int n = i / KCAT, k = i % KCAT;
    WcatB[i] = f2bf((k < TH_) ? Wih[n*TH_ + k] : Whh[n*ENC_ + (k - TH_)]);
  }
  if (i < GATE) biasg[i] = bih[i] + bhh[i];
  if (i < 2*ENC_*ENC_) {
    int n = i >> 7, k = i & 127;
    WkvB[i] = f2bf((n < ENC_) ? Wk[n*ENC_ + k] : Wv[(n-ENC_)*ENC_ + k]);
    Wg1B[i] = f2bf((n < ENC_) ? Wg1a[n*ENC_ + k] : Wg1g[(n-ENC_)*ENC_ + k]);
    Wg2B[i] = f2bf((n < ENC_) ? Wg2a[n*ENC_ + k] : Wg2g[(n-ENC_)*ENC_ + k]);
  }
  if (i < 2*ENC_) {
    bkv[i] = (i < ENC_) ? bk[i] : bv[i-ENC_];
    bg1[i] = (i < ENC_) ? bg1a[i] : bg1g[i-ENC_];
    bg2[i] = (i < ENC_) ? bg2a[i] : bg2g[i-ENC_];
  }
  if (i < ENC_*ENC_) WqB[i] = f2bf(Wq[i]);
  if (i < 3*ENC_*ENC_) {
    int n = i >> 7, k = i & 127;
    float w = (n < ENC_) ? Wqt[n*ENC_ + k] : (n < 2*ENC_) ? Wkt[(n-ENC_)*ENC_ + k]
                                                          : Wvt[(n-2*ENC_)*ENC_ + k];
    WqktB[i] = f2bf(w);
  }
  if (i < 3*ENC_) bqkt[i] = (i < ENC_) ? bqt[i] : (i < 2*ENC_) ? bkt[i-ENC_] : bvt[i-2*ENC_];
  if (i < MROWS*ENC_) { Ha[i] = 0; cbuf[i] = 0.0f; }
}

// ================= mask width detect / count / fill ==================================
__device__ __forceinline__ int cellval(const unsigned char* m, long cell, int w) {
  long byte = cell * 128L * w;
  if (w == 1) return m[byte] != 0;
  if (w == 2) return *(const unsigned short*)(m + byte) != 0;
  if (w == 4) return *(const unsigned int*)(m + byte) != 0;
  return *(const unsigned long long*)(m + byte) != 0ULL;
}
__device__ __forceinline__ int cellconsist(const unsigned char* m, long cell, int w) {
  long byte = cell * 128L * w;
  if (w == 1) { unsigned char v = m[byte];
    for (int j = 1; j < 8; ++j) if (m[byte + j] != v) return 0; return 1; }
  if (w == 2) { unsigned short v = *(const unsigned short*)(m + byte);
    for (int j = 1; j < 8; ++j) if (*(const unsigned short*)(m + byte + 2L*j) != v) return 0; return 1; }
  if (w == 4) { unsigned int v = *(const unsigned int*)(m + byte);
    for (int j = 1; j < 8; ++j) if (*(const unsigned int*)(m + byte + 4L*j) != v) return 0; return 1; }
  unsigned long long v = *(const unsigned long long*)(m + byte);
  for (int j = 1; j < 8; ++j) if (*(const unsigned long long*)(m + byte + 8L*j) != v) return 0; return 1;
}

__global__ void k_detect(const unsigned char* __restrict__ mask, int* __restrict__ wsel)
{
  __shared__ int bad;
  int tid = threadIdx.x;
  int chosen = 0;
  for (int w = 1; w <= 8 && !chosen; w <<= 1) {
    if (tid == 0) bad = 0;
    __syncthreads();
    int ok = 1;
    for (int c = tid; c < 512; c += 256) ok &= cellconsist(mask, c, w);
    if (!ok) bad = 1;
    __syncthreads();
    if (!bad) chosen = w;
    __syncthreads();
  }
  if (tid == 0) *wsel = chosen ? chosen : 1;
}

__global__ void k_count(const unsigned char* __restrict__ mask,
                        const int* __restrict__ wsel, int* __restrict__ bcnt)
{
  __shared__ int sc[256];
  int tid = threadIdx.x;
  long cell = (long)blockIdx.x*256 + tid;
  sc[tid] = cellval(mask, cell, *wsel);
  __syncthreads();
  for (int off = 128; off; off >>= 1) {
    if (tid < off) sc[tid] += sc[tid + off];
    __syncthreads();
  }
  if (tid == 0) bcnt[blockIdx.x] = sc[0];
}

__global__ void k_fill(const unsigned char* __restrict__ mask,
                       const int* __restrict__ wsel, const int* __restrict__ bcnt,
                       int* __restrict__ nidx)
{
  __shared__ int sc[256];
  int tid = threadIdx.x, blk = blockIdx.x;
  long cell = (long)blk*256 + tid;
  int on = cellval(mask, cell, *wsel);
  sc[tid] = on;
  __syncthreads();
  for (int off = 1; off < 256; off <<= 1) {
    int v = (tid >= off) ? sc[tid - off] : 0;
    __syncthreads();
    sc[tid] += v;
    __syncthreads();
  }
  int base = 0;
  for (int i = 0; i < blk; ++i) base += bcnt[i];
  nidx[cell] = on ? (base + sc[tid] - 1) : -1;
}

// ================= encode ALL t: elu(in5 @ W1^T + b1) -> XencB[t][m][64] bf16 =========
__global__ __launch_bounds__(256) void k_encode_all(
    const float* __restrict__ hist, const float* __restrict__ cls, const float* __restrict__ va,
    const float* __restrict__ nbrs, const float* __restrict__ nbrscls, const float* __restrict__ nbrsva,
    const float* __restrict__ W1, const float* __restrict__ b1,
    unsigned short* __restrict__ XencB)
{
  int i = blockIdx.x*256 + threadIdx.x;      // over MROWS*64
  int t = blockIdx.y;
  int o = i & 63, m = i >> 6;
  float in0, in1, in2, in3, in4;
  if (m < B_) {
    int r = t*B_ + m;
    in0 = hist[r*2]; in1 = hist[r*2+1]; in2 = cls[r]; in3 = va[r*2]; in4 = va[r*2+1];
  } else {
    int r = t*N_ + (m - B_);
    in0 = nbrs[r*2]; in1 = nbrs[r*2+1]; in2 = nbrscls[r]; in3 = nbrsva[r*2]; in4 = nbrsva[r*2+1];
  }
  const float* w = W1 + o*5;
  float s = b1[o] + in0*w[0] + in1*w[1] + in2*w[2] + in3*w[3] + in4*w[4];
  XencB[((long)t*MROWS + m)*64 + o] = f2bf((s > 0.0f) ? s : expm1f(s));
}

// ================= fused gate GEMM (bf16 MFMA) + LSTM cell ===========================
// grid (MROWS/64, 128/32); wave w computes gate w for 64 rows x 32 channels.
__global__ __launch_bounds__(256) void k_gate_cell(int t,
    const unsigned short* __restrict__ XencB, const unsigned short* __restrict__ Hc,
    const unsigned short* __restrict__ WcatB, const float* __restrict__ biasg,
    float* __restrict__ cbuf, unsigned short* __restrict__ Hn, float* __restrict__ hh)
{
  __shared__ float gl[4][64][32];     // 32 KiB
  int tid = threadIdx.x;
  int w = tid >> 6, l = tid & 63;
  int lr = l & 15, lk = (l >> 4) * 8, lq = (l >> 4) * 4;
  int bm = blockIdx.x * 64;
  int bnch = blockIdx.y * 32;
  const unsigned short* Xt = XencB + (long)t*MROWS*64;

  f32x4 acc[4][2] = {};
  #pragma unroll
  for (int it = 0; it < 6; ++it) {
    int k0 = it*32;
    const unsigned short* Ab = (k0 < 64) ? Xt : Hc;
    int alda = (k0 < 64) ? 64 : 128;
    int ak   = (k0 < 64) ? k0 : (k0 - 64);
    bf16x8 a[4], b[2];
    #pragma unroll
    for (int mi = 0; mi < 4; ++mi)
      a[mi] = *(const bf16x8*)(Ab + (long)(bm + mi*16 + lr)*alda + ak + lk);
    #pragma unroll
    for (int ni = 0; ni < 2; ++ni)
      b[ni] = *(const bf16x8*)(WcatB + (long)(w*128 + bnch + ni*16 + lr)*KCAT + k0 + lk);
    #pragma unroll
    for (int mi = 0; mi < 4; ++mi)
      #pragma unroll
      for (int ni = 0; ni < 2; ++ni)
        acc[mi][ni] = __builtin_amdgcn_mfma_f32_16x16x32_bf16(a[mi], b[ni], acc[mi][ni], 0, 0, 0);
  }
  #pragma unroll
  for (int mi = 0; mi < 4; ++mi)
    #pragma unroll
    for (int ni = 0; ni < 2; ++ni) {
      float bb = biasg[w*128 + bnch + ni*16 + lr];
      #pragma unroll
      for (int q = 0; q < 4; ++q)
        gl[w][mi*16 + lq + q][ni*16 + lr] = acc[mi][ni][q] + bb;
    }
  __syncthreads();
  for (int e = tid; e < 2048; e += 256) {
    int row = e >> 5, ch = e & 31;
    int gm = bm + row, gch = bnch + ch;
    float gi = gl[0][row][ch], gf = gl[1][row][ch], gg = gl[2][row][ch], go = gl[3][row][ch];
    long ci = (long)gm*ENC_ + gch;
    float cc = sigm(gf)*cbuf[ci] + sigm(gi)*tanhf(gg);
    cbuf[ci] = cc;
    float hv = sigm(go)*tanhf(cc);
    Hn[ci] = f2bf(hv);
    if (gm < B_) hh[((long)gm*T_ + t)*ENC_ + gch] = hv;
  }
}

// ================= generic bf16 MFMA GEMM: C[M,N] = A @ W^T + bias ====================
// grid (M/64, N/128); 4 waves, wave w owns cols [blockIdx.y*128 + w*32, +32).
__global__ __launch_bounds__(256) void k_gemm_bf16(
    const unsigned short* __restrict__ A, int lda,
    const unsigned short* __restrict__ W, int ldw,
    const float* __restrict__ bias,
    float* __restrict__ C, int ldc, int K)
{
  int tid = threadIdx.x;
  int w = tid >> 6, l = tid & 63;
  int lr = l & 15, lk = (l >> 4) * 8, lq = (l >> 4) * 4;
  int bm = blockIdx.x * 64;
  int bn = blockIdx.y * 128 + w * 32;
  f32x4 acc[4][2] = {};
  for (int k0 = 0; k0 < K; k0 += 32) {
    bf16x8 a[4], b[2];
    #pragma unroll
    for (int mi = 0; mi < 4; ++mi)
      a[mi] = *(const bf16x8*)(A + (long)(bm + mi*16 + lr)*lda + k0 + lk);
    #pragma unroll
    for (int ni = 0; ni < 2; ++ni)
      b[ni] = *(const bf16x8*)(W + (long)(bn + ni*16 + lr)*ldw + k0 + lk);
    #pragma unroll
    for (int mi = 0; mi < 4; ++mi)
      #pragma unroll
      for (int ni = 0; ni < 2; ++ni)
        acc[mi][ni] = __builtin_amdgcn_mfma_f32_16x16x32_bf16(a[mi], b[ni], acc[mi][ni], 0, 0, 0);
  }
  #pragma unroll
  for (int mi = 0; mi < 4; ++mi)
    #pragma unroll
    for (int ni = 0; ni < 2; ++ni) {
      int col = bn + ni*16 + lr;
      float bb = bias[col];
      #pragma unroll
      for (int q = 0; q < 4; ++q)
        C[(long)(bm + mi*16 + lq + q)*ldc + col] = acc[mi][ni][q] + bb;
    }
}

// ================= spatial attention (q folded in): block per b, 128 threads ==========
__global__ __launch_bounds__(128) void k_attn_sp(int t,
    const unsigned short* __restrict__ H, const unsigned short* __restrict__ WqB,
    const float* __restrict__ bq,
    const float* __restrict__ knv,           // (N,256): k | v
    const float* __restrict__ bk, const float* __restrict__ bv,
    const int* __restrict__ nidx, unsigned short* __restrict__ spaB)
{
  int b = blockIdx.x;
  int tid = threadIdx.x;              // 128 = 4 heads x 32
  int h2 = tid >> 5, d = tid & 31;
  __shared__ float sh_h[128];
  __shared__ float sq2[128];
  __shared__ float aw[4][40];
  __shared__ int sn[G_];
  if (tid < G_) sn[tid] = nidx[b*G_ + tid];
  sh_h[tid] = bf2f(H[(long)b*ENC_ + tid]);
  __syncthreads();
  // q[tid] = h . Wq[tid] + bq[tid]
  {
    const unsigned short* wr = WqB + (long)tid*ENC_;
    float acc = bq[tid];
    #pragma unroll 4
    for (int k = 0; k < ENC_; ++k) acc += sh_h[k] * bf2f(wr[k]);
    sq2[tid] = acc;
  }
  __syncthreads();
  float qv = sq2[tid];
  for (int g = 0; g < G_; ++g) {
    int ni = sn[g];
    float kv = (ni >= 0) ? knv[(long)ni*256 + tid] : bk[tid];
    float pp = qv * kv;
    pp += __shfl_xor(pp, 16); pp += __shfl_xor(pp, 8);
    pp += __shfl_xor(pp, 4);  pp += __shfl_xor(pp, 2); pp += __shfl_xor(pp, 1);
    if (d == 0) aw[h2][g] = pp * SCALE_;
  }
  __syncthreads();
  float mx = -1e30f;
  for (int g = d; g < G_; g += 32) mx = fmaxf(mx, aw[h2][g]);
  for (int off = 16; off; off >>= 1) mx = fmaxf(mx, __shfl_xor(mx, off));
  float sum = 0.0f;
  for (int g = d; g < G_; g += 32) { float e = expf(aw[h2][g] - mx); aw[h2][g] = e; sum += e; }
  for (int off = 16; off; off >>= 1) sum += __shfl_xor(sum, off);
  float inv = 1.0f / sum;
  __syncthreads();
  float acc = 0.0f;
  for (int g = 0; g < G_; ++g) {
    int ni = sn[g];
    float vv = (ni >= 0) ? knv[(long)ni*256 + 128 + tid] : bv[tid];
    acc += aw[h2][g] * vv;
  }
  spaB[((long)b*T_ + t)*ENC_ + tid] = f2bf(acc * inv);
}

// ================= GLU elementwise from fused (row,256) buffer =======================
__global__ __launch_bounds__(256) void k_glumul(
    const float* __restrict__ t12, float* __restrict__ o, int n)
{
  int i = blockIdx.x*256 + threadIdx.x;
  if (i < n) {
    int row = i >> 7, c = i & 127;
    o[i] = t12[(long)row*256 + c] * sigm(t12[(long)row*256 + 128 + c]);
  }
}

// ================= fused add + layernorm =============================================
__global__ __launch_bounds__(256) void k_addln(
    const float* __restrict__ A, const float* __restrict__ Bv,
    const float* __restrict__ g, const float* __restrict__ bb,
    float* __restrict__ sum_out, float* __restrict__ ln_f32,
    unsigned short* __restrict__ ln_bf16, int rows)
{
  int gtid = blockIdx.x*256 + threadIdx.x;
  int w = gtid >> 6;
  int lane = threadIdx.x & 63;
  if (w >= rows) return;
  long base = (long)w*ENC_;
  float x0 = A[base + lane]      + Bv[base + lane];
  float x1 = A[base + 64 + lane] + Bv[base + 64 + lane];
  if (sum_out) { sum_out[base + lane] = x0; sum_out[base + 64 + lane] = x1; }
  float s = x0 + x1, s2 = x0*x0 + x1*x1;
  for (int off = 32; off; off >>= 1) { s += __shfl_xor(s, off); s2 += __shfl_xor(s2, off); }
  float mean = s * (1.0f/128.0f);
  float var  = s2 * (1.0f/128.0f) - mean*mean;
  float inv  = rsqrtf(var + LNEPS);
  float o0 = (x0 - mean)*inv*g[lane]      + bb[lane];
  float o1 = (x1 - mean)*inv*g[64 + lane] + bb[64 + lane];
  if (ln_f32)  { ln_f32[base + lane] = o0;       ln_f32[base + 64 + lane] = o1; }
  if (ln_bf16) { ln_bf16[base + lane] = f2bf(o0); ln_bf16[base + 64 + lane] = f2bf(o1); }
}

// ================= temporal attention: block per b, 128 threads ======================
__global__ __launch_bounds__(128) void k_attn_t(
    const float* __restrict__ qkt, unsigned short* __restrict__ out)
{
  int b = blockIdx.x, tid = threadIdx.x;
  __shared__ float sq[16][128], sk[16][128], sv[16][128];
  __shared__ float sc[16][4][16];     // [t][h][s]
  for (int i = tid; i < T_*ENC_; i += 128) {
    int tt = i >> 7, j = i & 127;
    long a = ((long)b*T_ + tt)*384;
    sq[tt][j] = qkt[a + j]; sk[tt][j] = qkt[a + 128 + j]; sv[tt][j] = qkt[a + 256 + j];
  }
  __syncthreads();
  for (int e = tid; e < 1024; e += 128) {
    int t = e >> 6, s = (e >> 2) & 15, h2 = e & 3;
    float pp = 0.0f;
    #pragma unroll
    for (int d2 = 0; d2 < 32; ++d2) pp += sq[t][h2*32 + d2] * sk[s][h2*32 + d2];
    sc[t][h2][s] = pp * SCALE_;
  }
  __syncthreads();
  if (tid < 64) {
    int t = tid >> 2, h2 = tid & 3;
    float mx = -1e30f;
    for (int s = 0; s < 16; ++s) mx = fmaxf(mx, sc[t][h2][s]);
    float sum = 0.0f;
    for (int s = 0; s < 16; ++s) { float e2 = expf(sc[t][h2][s] - mx); sc[t][h2][s] = e2; sum += e2; }
    float inv = 1.0f / sum;
    for (int s = 0; s < 16; ++s) sc[t][h2][s] *= inv;
  }
  __syncthreads();
  int h2 = tid >> 5, d2 = tid & 31;
  for (int t = 0; t < 16; ++t) {
    float acc = 0.0f;
    for (int s = 0; s < 16; ++s) acc += sc[t][h2][s] * sv[s][h2*32 + d2];
    out[((long)b*T_ + t)*ENC_ + tid] = f2bf(acc);
  }
}

extern "C" void kernel_launch(void* const* d_in, const int* in_sizes, int n_in,
                              void* d_out, int out_size, void* d_ws, size_t ws_size,
                              hipStream_t stream)
{
  const float* hist    = (const float*)d_in[0];
  const float* nbrs    = (const float*)d_in[1];
  const float* va      = (const float*)d_in[2];
  const float* nbrsva  = (const float*)d_in[3];
  const float* cls     = (const float*)d_in[6];
  const float* nbrscls = (const float*)d_in[7];
  const unsigned char* mask = (const unsigned char*)d_in[8];
  const float* W1  = (const float*)d_in[9];
  const float* b1  = (const float*)d_in[10];
  const float* Wih = (const float*)d_in[11];
  const float* Whh = (const float*)d_in[12];
  const float* bih = (const float*)d_in[13];
  const float* bhh = (const float*)d_in[14];
  const float* Wq  = (const float*)d_in[15];
  const float* bq  = (const float*)d_in[16];
  const float* Wk  = (const float*)d_in[17];
  const float* bk  = (const float*)d_in[18];
  const float* Wv  = (const float*)d_in[19];
  const float* bv  = (const float*)d_in[20];
  const float* Wg1a = (const float*)d_in[21];
  const float* bg1a = (const float*)d_in[22];
  const float* Wg1g = (const float*)d_in[23];
  const float* bg1g = (const float*)d_in[24];
  const float* Wqt = (const float*)d_in[25];
  const float* bqt = (const float*)d_in[26];
  const float* Wkt = (const float*)d_in[27];
  const float* bkt = (const float*)d_in[28];
  const float* Wvt = (const float*)d_in[29];
  const float* bvt = (const float*)d_in[30];
  const float* Wg2a = (const float*)d_in[31];
  const float* bg2a = (const float*)d_in[32];
  const float* Wg2g = (const float*)d_in[33];
  const float* bg2g = (const float*)d_in[34];
  const float* ln_g = (const float*)d_in[35];
  const float* ln_b = (const float*)d_in[36];

  // ---- workspace layout (bytes, 256B aligned chunks) ----
  char* base = (char*)d_ws;
  size_t off = 0;
  auto alloc = [&](size_t bytes) { char* r = base + off; off = (off + bytes + 255) & ~(size_t)255; return r; };
  unsigned short* WcatB = (unsigned short*)alloc(GATE*KCAT*2);
  float*          biasg = (float*)alloc(GATE*4);
  unsigned short* WkvB  = (unsigned short*)alloc(2*ENC_*ENC_*2);
  float*          bkv   = (float*)alloc(2*ENC_*4);
  unsigned short* WqB   = (unsigned short*)alloc(ENC_*ENC_*2);
  unsigned short* WqktB = (unsigned short*)alloc(3*ENC_*ENC_*2);
  float*          bqkt  = (float*)alloc(3*ENC_*4);
  unsigned short* Wg1B  = (unsigned short*)alloc(2*ENC_*ENC_*2);
  float*          bg1   = (float*)alloc(2*ENC_*4);
  unsigned short* Wg2B  = (unsigned short*)alloc(2*ENC_*ENC_*2);
  float*          bg2   = (float*)alloc(2*ENC_*4);
  unsigned short* XencB = (unsigned short*)alloc((size_t)T_*MROWS*64*2);
  unsigned short* Ha    = (unsigned short*)alloc((size_t)MROWS*ENC_*2);
  unsigned short* Hb    = (unsigned short*)alloc((size_t)MROWS*ENC_*2);
  float*          cbuf  = (float*)alloc((size_t)MROWS*ENC_*4);
  float*          hh    = (float*)alloc((size_t)B_*T_*ENC_*4);
  float*          knv   = (float*)alloc((size_t)N_*2*ENC_*4);
  unsigned short* spaB  = (unsigned short*)alloc((size_t)B_*T_*ENC_*2);
  float*          t12   = (float*)alloc((size_t)B_*T_*2*ENC_*4);
  float*          spaG  = (float*)alloc((size_t)B_*T_*ENC_*4);
  float*          S1    = (float*)alloc((size_t)B_*T_*ENC_*4);
  unsigned short* valsB = (unsigned short*)alloc((size_t)B_*T_*ENC_*2);
  float*          qkt   = (float*)alloc((size_t)B_*T_*3*ENC_*4);
  unsigned short* atoB  = (unsigned short*)alloc((size_t)B_*T_*ENC_*2);
  float*          tG2   = (float*)alloc((size_t)B_*T_*ENC_*4);
  int*            nidx  = (int*)alloc((size_t)B_*G_*4);
  int*            bcnt  = (int*)alloc(78*4);
  int*            wsel  = (int*)alloc(4);

  const int ROWS = B_*T_;                    // 8192
  const int NELT = ROWS*ENC_;                // 1,048,576

  k_prep<<<(MROWS*ENC_ + 255)/256, 256, 0, stream>>>(
      Wih, Whh, bih, bhh, Wk, bk, Wv, bv, Wq,
      Wqt, bqt, Wkt, bkt, Wvt, bvt,
      Wg1a, bg1a, Wg1g, bg1g, Wg2a, bg2a, Wg2g, bg2g,
      WcatB, biasg, WkvB, bkv, WqB, WqktB, bqkt, Wg1B, bg1, Wg2B, bg2,
      Ha, cbuf);
  k_detect<<<1, 256, 0, stream>>>(mask, wsel);
  k_count<<<78, 256, 0, stream>>>(mask, wsel, bcnt);
  k_fill<<<78, 256, 0, stream>>>(mask, wsel, bcnt, nidx);
  k_encode_all<<<dim3(MROWS*64/256, T_), 256, 0, stream>>>(
      hist, cls, va, nbrs, nbrscls, nbrsva, W1, b1, XencB);

  unsigned short* Hc = Ha;
  unsigned short* Hn = Hb;
  for (int t = 0; t < T_; ++t) {
    k_gate_cell<<<dim3(MROWS/64, 4), 256, 0, stream>>>(
        t, XencB, Hc, WcatB, biasg, cbuf, Hn, hh);
    k_gemm_bf16<<<dim3(N_/64, 2), 256, 0, stream>>>(
        Hn + (long)B_*ENC_, ENC_, WkvB, ENC_, bkv, knv, 2*ENC_, ENC_);
    k_attn_sp<<<B_, 128, 0, stream>>>(t, Hn, WqB, bq, knv, bk, bv, nidx, spaB);
    unsigned short* tmp = Hc; Hc = Hn; Hn = tmp;
  }

  // GLU1 (fused a|g), spaG = glu(spa)
  k_gemm_bf16<<<dim3(ROWS/64, 2), 256, 0, stream>>>(spaB, ENC_, Wg1B, ENC_, bg1, t12, 2*ENC_, ENC_);
  k_glumul<<<(NELT + 255)/256, 256, 0, stream>>>(t12, spaG, NELT);
  // S1 = hh + spaG ; vals = LN(S1) (bf16)
  k_addln<<<(ROWS*64 + 255)/256, 256, 0, stream>>>(hh, spaG, ln_g, ln_b, S1, nullptr, valsB, ROWS);
  // temporal q|k|v in one GEMM
  k_gemm_bf16<<<dim3(ROWS/64, 3), 256, 0, stream>>>(valsB, ENC_, WqktB, ENC_, bqkt, qkt, 3*ENC_, ENC_);
  k_attn_t<<<B_, 128, 0, stream>>>(qkt, atoB);
  // GLU2
  k_gemm_bf16<<<dim3(ROWS/64, 2), 256, 0, stream>>>(atoB, ENC_, Wg2B, ENC_, bg2, t12, 2*ENC_, ENC_);
  k_glumul<<<(NELT + 255)/256, 256, 0, stream>>>(t12, tG2, NELT);
  // out = LN(S1 + tG2) (f32)
  k_addln<<<(ROWS*64 + 255)/256, 256, 0, stream>>>(S1, tG2, ln_g, ln_b, nullptr, (float*)d_out, nullptr, ROWS);
}

// Round 5
// 513.916 us; speedup vs baseline: 3.1102x; 1.7522x over previous
//
#include <hip/hip_runtime.h>
#include <math.h>

#define T_ 16
#define B_ 512
#define N_ 8192
#define G_ 39
#define ENC_ 128
#define TH_ 64
#define MROWS 8704          // B_ + N_
#define GATE 512            // 4*ENC_
#define KCAT 192            // TH_ + ENC_
#define SCALE_ 0.08838834764831845f
#define LNEPS 1e-5f
#define NBLK 136            // MROWS/64

typedef short bf16x8 __attribute__((ext_vector_type(8)));
typedef float f32x4  __attribute__((ext_vector_type(4)));

__device__ __forceinline__ float sigm(float x){ return 1.0f/(1.0f+expf(-x)); }
__device__ __forceinline__ unsigned short f2bf(float f){
  unsigned int u = __float_as_uint(f);
  unsigned int r = u + 0x7FFFu + ((u>>16)&1u);
  return (unsigned short)(r>>16);
}
__device__ __forceinline__ float bf2f(unsigned short h){
  return __uint_as_float(((unsigned int)h)<<16);
}

// ================= prep: convert weights to bf16, build fused biases =================
__global__ __launch_bounds__(256) void k_prep(
    const float* __restrict__ Wih, const float* __restrict__ Whh,
    const float* __restrict__ bih, const float* __restrict__ bhh,
    const float* __restrict__ Wk,  const float* __restrict__ bk,
    const float* __restrict__ Wv,  const float* __restrict__ bv,
    const float* __restrict__ Wq,
    const float* __restrict__ Wqt, const float* __restrict__ bqt,
    const float* __restrict__ Wkt, const float* __restrict__ bkt,
    const float* __restrict__ Wvt, const float* __restrict__ bvt,
    const float* __restrict__ Wg1a, const float* __restrict__ bg1a,
    const float* __restrict__ Wg1g, const float* __restrict__ bg1g,
    const float* __restrict__ Wg2a, const float* __restrict__ bg2a,
    const float* __restrict__ Wg2g, const float* __restrict__ bg2g,
    unsigned short* __restrict__ WcatB, float* __restrict__ biasg,
    unsigned short* __restrict__ WkvB,  float* __restrict__ bkv,
    unsigned short* __restrict__ WqB,
    unsigned short* __restrict__ WqktB, float* __restrict__ bqkt,
    unsigned short* __restrict__ Wg1B,  float* __restrict__ bg1,
    unsigned short* __restrict__ Wg2B,  float* __restrict__ bg2)
{
  int i = blockIdx.x*256 + threadIdx.x;
  if (i < GATE*KCAT) {
    int n = i / KCAT, k = i % KCAT;
    WcatB[i] = f2bf((k < TH_) ? Wih[n*TH_ + k] : Whh[n*ENC_ + (k - TH_)]);
  }
  if (i < GATE) biasg[i] = bih[i] + bhh[i];
  if (i < 2*ENC_*ENC_) {
    int n = i >> 7, k = i & 127;
    WkvB[i] = f2bf((n < ENC_) ? Wk[n*ENC_ + k] : Wv[(n-ENC_)*ENC_ + k]);
    Wg1B[i] = f2bf((n < ENC_) ? Wg1a[n*ENC_ + k] : Wg1g[(n-ENC_)*ENC_ + k]);
    Wg2B[i] = f2bf((n < ENC_) ? Wg2a[n*ENC_ + k] : Wg2g[(n-ENC_)*ENC_ + k]);
  }
  if (i < 2*ENC_) {
    bkv[i] = (i < ENC_) ? bk[i] : bv[i-ENC_];
    bg1[i] = (i < ENC_) ? bg1a[i] : bg1g[i-ENC_];
    bg2[i] = (i < ENC_) ? bg2a[i] : bg2g[i-ENC_];
  }
  if (i < ENC_*ENC_) WqB[i] = f2bf(Wq[i]);
  if (i < 3*ENC_*ENC_) {
    int n = i >> 7, k = i & 127;
    float w = (n < ENC_) ? Wqt[n*ENC_ + k] : (n < 2*ENC_) ? Wkt[(n-ENC_)*ENC_ + k]
                                                          : Wvt[(n-2*ENC_)*ENC_ + k];
    WqktB[i] = f2bf(w);
  }
  if (i < 3*ENC_) bqkt[i] = (i < ENC_) ? bqt[i] : (i < 2*ENC_) ? bkt[i-ENC_] : bvt[i-2*ENC_];
}

// ================= mask width detect / count / fill (proven R3) ======================
__device__ __forceinline__ int cellval(const unsigned char* m, long cell, int w) {
  long byte = cell * 128L * w;
  if (w == 1) return m[byte] != 0;
  if (w == 2) return *(const unsigned short*)(m + byte) != 0;
  if (w == 4) return *(const unsigned int*)(m + byte) != 0;
  return *(const unsigned long long*)(m + byte) != 0ULL;
}
__device__ __forceinline__ int cellconsist(const unsigned char* m, long cell, int w) {
  long byte = cell * 128L * w;
  if (w == 1) { unsigned char v = m[byte];
    for (int j = 1; j < 8; ++j) if (m[byte + j] != v) return 0; return 1; }
  if (w == 2) { unsigned short v = *(const unsigned short*)(m + byte);
    for (int j = 1; j < 8; ++j) if (*(const unsigned short*)(m + byte + 2L*j) != v) return 0; return 1; }
  if (w == 4) { unsigned int v = *(const unsigned int*)(m + byte);
    for (int j = 1; j < 8; ++j) if (*(const unsigned int*)(m + byte + 4L*j) != v) return 0; return 1; }
  unsigned long long v = *(const unsigned long long*)(m + byte);
  for (int j = 1; j < 8; ++j) if (*(const unsigned long long*)(m + byte + 8L*j) != v) return 0; return 1;
}

__global__ void k_detect(const unsigned char* __restrict__ mask, int* __restrict__ wsel)
{
  __shared__ int bad;
  int tid = threadIdx.x;
  int chosen = 0;
  for (int w = 1; w <= 8 && !chosen; w <<= 1) {
    if (tid == 0) bad = 0;
    __syncthreads();
    int ok = 1;
    for (int c = tid; c < 512; c += 256) ok &= cellconsist(mask, c, w);
    if (!ok) bad = 1;
    __syncthreads();
    if (!bad) chosen = w;
    __syncthreads();
  }
  if (tid == 0) *wsel = chosen ? chosen : 1;
}

__global__ void k_count(const unsigned char* __restrict__ mask,
                        const int* __restrict__ wsel, int* __restrict__ bcnt)
{
  __shared__ int sc[256];
  int tid = threadIdx.x;
  long cell = (long)blockIdx.x*256 + tid;
  sc[tid] = cellval(mask, cell, *wsel);
  __syncthreads();
  for (int off = 128; off; off >>= 1) {
    if (tid < off) sc[tid] += sc[tid + off];
    __syncthreads();
  }
  if (tid == 0) bcnt[blockIdx.x] = sc[0];
}

__global__ void k_fill(const unsigned char* __restrict__ mask,
                       const int* __restrict__ wsel, const int* __restrict__ bcnt,
                       int* __restrict__ nidx)
{
  __shared__ int sc[256];
  int tid = threadIdx.x, blk = blockIdx.x;
  long cell = (long)blk*256 + tid;
  int on = cellval(mask, cell, *wsel);
  sc[tid] = on;
  __syncthreads();
  for (int off = 1; off < 256; off <<= 1) {
    int v = (tid >= off) ? sc[tid - off] : 0;
    __syncthreads();
    sc[tid] += v;
    __syncthreads();
  }
  int base = 0;
  for (int i = 0; i < blk; ++i) base += bcnt[i];
  nidx[cell] = on ? (base + sc[tid] - 1) : -1;
}

// ================= kernel A: fused encode + LSTM chunk + kv/q projections ============
struct AP {
  const float *hist, *cls, *va, *nbrs, *nbrscls, *nbrsva;
  const float *W1, *b1;
  const unsigned short *Wcat, *Wkv, *Wq;
  const float *biasg, *bkv, *bq;
  float *hh;                 // (B,T,128) f32
  float *qbuf;               // (T,B,128) f32
  unsigned short *knvB;      // (tch,N,256) bf16
  unsigned short *Hsp;       // (MROWS,128) bf16 spill (swizzled content)
  float *csp;                // (NBLK, 64*132) f32 spill
  int c0, tch;
};

__global__ __launch_bounds__(256, 1) void k_lstm(AP p)
{
  __shared__ unsigned short Hl[2*64*128];   // double-buffered, XOR-swizzled
  __shared__ float cl[64*132];              // c-state, padded
  __shared__ unsigned short Xl[64*64];      // encoded inputs, XOR-swizzled
  __shared__ float inl[64][8];              // raw 5-feature staging

  const int tid = threadIdx.x;
  const int w = tid >> 6, l = tid & 63;
  const int lr = l & 15, lk = (l >> 4) * 8, lq = (l >> 4) * 4;
  const int bi = blockIdx.x, bm = bi * 64;
  const bool ish = (bi < 8);
  const int c = tid & 63;

  // hoist W1 row for my column
  float w1c0 = p.W1[c*5+0], w1c1 = p.W1[c*5+1], w1c2 = p.W1[c*5+2],
        w1c3 = p.W1[c*5+3], w1c4 = p.W1[c*5+4], b1c = p.b1[c];

  // restore / init state
  if (p.c0 == 0) {
    for (int i = tid; i < 64*128; i += 256) Hl[i] = 0;
    for (int i = tid; i < 64*132; i += 256) cl[i] = 0.0f;
  } else {
    for (int i = tid; i < 64*128; i += 256) Hl[i] = p.Hsp[(long)bm*128 + i];
    for (int i = tid; i < 64*132; i += 256) cl[i] = p.csp[(long)bi*8448 + i];
  }
  __syncthreads();

  int cur = 0;
  for (int tl = 0; tl < p.tch; ++tl) {
    int t = p.c0 + tl;
    // ---- stage raw 5-feature inputs for own 64 rows ----
    for (int idx = tid; idx < 320; idx += 256) {
      int row = idx / 5, f = idx - row*5;
      long r = ish ? ((long)t*B_ + bm + row) : ((long)t*N_ + (bm - B_) + row);
      const float* ph = ish ? p.hist : p.nbrs;
      const float* pc = ish ? p.cls  : p.nbrscls;
      const float* pv = ish ? p.va   : p.nbrsva;
      inl[row][f] = (f < 2) ? ph[r*2 + f] : (f == 2) ? pc[r] : pv[r*2 + (f-3)];
    }
    __syncthreads();
    // ---- encode: elu(in5 . W1[c]) -> Xl (swizzled) ----
    {
      int rg = tid >> 6;
      #pragma unroll
      for (int j = 0; j < 16; ++j) {
        int row = rg*16 + j;
        float s = b1c + inl[row][0]*w1c0 + inl[row][1]*w1c1 + inl[row][2]*w1c2
                      + inl[row][3]*w1c3 + inl[row][4]*w1c4;
        s = (s > 0.0f) ? s : expm1f(s);
        Xl[row*64 + (c ^ ((row & 7) << 3))] = f2bf(s);
      }
    }
    __syncthreads();
    // ---- gate GEMM: all 4 gates for this wave's 32 channels ----
    f32x4 acc[4][4][2] = {};
    #pragma unroll
    for (int ks = 0; ks < 2; ++ks) {          // K 0..63 from Xl
      int k0 = ks*32;
      bf16x8 a[4];
      #pragma unroll
      for (int mi = 0; mi < 4; ++mi) {
        int row = mi*16 + lr;
        int col = (k0 + lk) ^ ((row & 7) << 3);
        a[mi] = *(const bf16x8*)(Xl + row*64 + col);
      }
      #pragma unroll
      for (int g4 = 0; g4 < 4; ++g4)
        #pragma unroll
        for (int ni = 0; ni < 2; ++ni) {
          bf16x8 b = *(const bf16x8*)(p.Wcat + (long)(g4*128 + w*32 + ni*16 + lr)*KCAT + k0 + lk);
          #pragma unroll
          for (int mi = 0; mi < 4; ++mi)
            acc[g4][mi][ni] = __builtin_amdgcn_mfma_f32_16x16x32_bf16(a[mi], b, acc[g4][mi][ni], 0, 0, 0);
        }
    }
    #pragma unroll
    for (int ks = 0; ks < 4; ++ks) {          // K 64..191 from Hl[cur]
      int k0 = ks*32;
      bf16x8 a[4];
      #pragma unroll
      for (int mi = 0; mi < 4; ++mi) {
        int row = mi*16 + lr;
        int col = (k0 + lk) ^ ((row & 7) << 3);
        a[mi] = *(const bf16x8*)(Hl + cur*8192 + row*128 + col);
      }
      #pragma unroll
      for (int g4 = 0; g4 < 4; ++g4)
        #pragma unroll
        for (int ni = 0; ni < 2; ++ni) {
          bf16x8 b = *(const bf16x8*)(p.Wcat + (long)(g4*128 + w*32 + ni*16 + lr)*KCAT + 64 + k0 + lk);
          #pragma unroll
          for (int mi = 0; mi < 4; ++mi)
            acc[g4][mi][ni] = __builtin_amdgcn_mfma_f32_16x16x32_bf16(a[mi], b, acc[g4][mi][ni], 0, 0, 0);
        }
    }
    // ---- lane-local cell update ----
    int nxt = cur ^ 1;
    #pragma unroll
    for (int mi = 0; mi < 4; ++mi)
      #pragma unroll
      for (int ni = 0; ni < 2; ++ni) {
        int ch = w*32 + ni*16 + lr;
        float bgi = p.biasg[ch], bgf = p.biasg[128+ch], bgg = p.biasg[256+ch], bgo = p.biasg[384+ch];
        #pragma unroll
        for (int q = 0; q < 4; ++q) {
          int row = mi*16 + lq + q;
          float gi = acc[0][mi][ni][q] + bgi;
          float gf = acc[1][mi][ni][q] + bgf;
          float gg = acc[2][mi][ni][q] + bgg;
          float go = acc[3][mi][ni][q] + bgo;
          float cc = sigm(gf)*cl[row*132 + ch] + sigm(gi)*tanhf(gg);
          cl[row*132 + ch] = cc;
          float hv = sigm(go)*tanhf(cc);
          Hl[nxt*8192 + row*128 + (ch ^ ((row & 7) << 3))] = f2bf(hv);
          if (ish) p.hh[((long)(bm + row)*T_ + t)*128 + ch] = hv;
        }
      }
    __syncthreads();
    cur = nxt;
    // ---- projections from new H: kv (nbr blocks) / q (hist blocks) ----
    if (!ish) {
      f32x4 a2[4][4] = {};
      #pragma unroll
      for (int ks = 0; ks < 4; ++ks) {
        int k0 = ks*32;
        bf16x8 a[4];
        #pragma unroll
        for (int mi = 0; mi < 4; ++mi) {
          int row = mi*16 + lr;
          int col = (k0 + lk) ^ ((row & 7) << 3);
          a[mi] = *(const bf16x8*)(Hl + cur*8192 + row*128 + col);
        }
        #pragma unroll
        for (int ni = 0; ni < 4; ++ni) {
          bf16x8 b = *(const bf16x8*)(p.Wkv + (long)(w*64 + ni*16 + lr)*128 + k0 + lk);
          #pragma unroll
          for (int mi = 0; mi < 4; ++mi)
            a2[mi][ni] = __builtin_amdgcn_mfma_f32_16x16x32_bf16(a[mi], b, a2[mi][ni], 0, 0, 0);
        }
      }
      long nr = bm - B_;
      #pragma unroll
      for (int mi = 0; mi < 4; ++mi)
        #pragma unroll
        for (int ni = 0; ni < 4; ++ni) {
          int ch = w*64 + ni*16 + lr;
          float bb = p.bkv[ch];
          #pragma unroll
          for (int q = 0; q < 4; ++q)
            p.knvB[((long)tl*N_ + nr + mi*16 + lq + q)*256 + ch] = f2bf(a2[mi][ni][q] + bb);
        }
    } else {
      f32x4 a2[4][2] = {};
      #pragma unroll
      for (int ks = 0; ks < 4; ++ks) {
        int k0 = ks*32;
        bf16x8 a[4];
        #pragma unroll
        for (int mi = 0; mi < 4; ++mi) {
          int row = mi*16 + lr;
          int col = (k0 + lk) ^ ((row & 7) << 3);
          a[mi] = *(const bf16x8*)(Hl + cur*8192 + row*128 + col);
        }
        #pragma unroll
        for (int ni = 0; ni < 2; ++ni) {
          bf16x8 b = *(const bf16x8*)(p.Wq + (long)(w*32 + ni*16 + lr)*128 + k0 + lk);
          #pragma unroll
          for (int mi = 0; mi < 4; ++mi)
            a2[mi][ni] = __builtin_amdgcn_mfma_f32_16x16x32_bf16(a[mi], b, a2[mi][ni], 0, 0, 0);
        }
      }
      #pragma unroll
      for (int mi = 0; mi < 4; ++mi)
        #pragma unroll
        for (int ni = 0; ni < 2; ++ni) {
          int ch = w*32 + ni*16 + lr;
          float bb = p.bq[ch];
          #pragma unroll
          for (int q = 0; q < 4; ++q)
            p.qbuf[((long)t*B_ + bm + mi*16 + lq + q)*128 + ch] = a2[mi][ni][q] + bb;
        }
    }
    __syncthreads();
  }
  // spill state for next chunk
  for (int i = tid; i < 64*128; i += 256) p.Hsp[(long)bm*128 + i] = Hl[cur*8192 + i];
  for (int i = tid; i < 64*132; i += 256) p.csp[(long)bi*8448 + i] = cl[i];
}

// ================= kernel B: spatial attention, one wave per (b, t) ==================
__global__ __launch_bounds__(256) void k_attn_sp(
    int c0, int ltch,
    const float* __restrict__ qbuf, const unsigned short* __restrict__ knvB,
    const float* __restrict__ bk, const float* __restrict__ bv,
    const int* __restrict__ nidx, unsigned short* __restrict__ spaB)
{
  int tid = threadIdx.x;
  int w = tid >> 6, l = tid & 63;
  __shared__ int sn[4][G_];
  __shared__ float aw[4][4][40];
  int gwid = blockIdx.x*4 + w;
  int b = gwid >> ltch;
  int tl = gwid & ((1 << ltch) - 1);
  int t = c0 + tl;
  if (l < G_) sn[w][l] = nidx[b*G_ + l];
  __syncthreads();
  float qA = qbuf[((long)t*B_ + b)*128 + l];
  float qB = qbuf[((long)t*B_ + b)*128 + 64 + l];
  for (int g = 0; g < G_; ++g) {
    int ni = sn[w][g];
    const unsigned short* kr = knvB + ((long)tl*N_ + ni)*256;
    float kA = (ni >= 0) ? bf2f(kr[l])      : bk[l];
    float kB = (ni >= 0) ? bf2f(kr[64 + l]) : bk[64 + l];
    float pA = qA*kA, pB = qB*kB;
    pA += __shfl_xor(pA, 16); pA += __shfl_xor(pA, 8); pA += __shfl_xor(pA, 4);
    pA += __shfl_xor(pA, 2);  pA += __shfl_xor(pA, 1);
    pB += __shfl_xor(pB, 16); pB += __shfl_xor(pB, 8); pB += __shfl_xor(pB, 4);
    pB += __shfl_xor(pB, 2);  pB += __shfl_xor(pB, 1);
    if ((l & 31) == 0) {
      int hb = l >> 5;
      aw[w][hb][g]     = pA * SCALE_;
      aw[w][2+hb][g]   = pB * SCALE_;
    }
  }
  __syncthreads();
  int hA = l >> 5, hB = 2 + (l >> 5);
  float mxA = -1e30f, mxB = -1e30f;
  for (int g = 0; g < G_; ++g) {
    mxA = fmaxf(mxA, aw[w][hA][g]);
    mxB = fmaxf(mxB, aw[w][hB][g]);
  }
  float sA = 0.f, sB = 0.f, oA = 0.f, oB = 0.f;
  for (int g = 0; g < G_; ++g) {
    int ni = sn[w][g];
    const unsigned short* vr = knvB + ((long)tl*N_ + ni)*256 + 128;
    float vA = (ni >= 0) ? bf2f(vr[l])      : bv[l];
    float vB = (ni >= 0) ? bf2f(vr[64 + l]) : bv[64 + l];
    float eA = expf(aw[w][hA][g] - mxA);
    float eB = expf(aw[w][hB][g] - mxB);
    sA += eA; sB += eB; oA += eA*vA; oB += eB*vB;
  }
  spaB[((long)b*T_ + t)*128 + l]      = f2bf(oA / sA);
  spaB[((long)b*T_ + t)*128 + 64 + l] = f2bf(oB / sB);
}

// ================= bf16 MFMA GEMM (proven R3): C f32 out =============================
__global__ __launch_bounds__(256) void k_gemm_bf16(
    const unsigned short* __restrict__ A, int lda,
    const unsigned short* __restrict__ W, int ldw,
    const float* __restrict__ bias,
    float* __restrict__ C, int ldc, int K)
{
  int tid = threadIdx.x;
  int w = tid >> 6, l = tid & 63;
  int lr = l & 15, lk = (l >> 4) * 8, lq = (l >> 4) * 4;
  int bm = blockIdx.x * 64;
  int bn = blockIdx.y * 128 + w * 32;
  f32x4 acc[4][2] = {};
  for (int k0 = 0; k0 < K; k0 += 32) {
    bf16x8 a[4], b[2];
    #pragma unroll
    for (int mi = 0; mi < 4; ++mi)
      a[mi] = *(const bf16x8*)(A + (long)(bm + mi*16 + lr)*lda + k0 + lk);
    #pragma unroll
    for (int ni = 0; ni < 2; ++ni)
      b[ni] = *(const bf16x8*)(W + (long)(bn + ni*16 + lr)*ldw + k0 + lk);
    #pragma unroll
    for (int mi = 0; mi < 4; ++mi)
      #pragma unroll
      for (int ni = 0; ni < 2; ++ni)
        acc[mi][ni] = __builtin_amdgcn_mfma_f32_16x16x32_bf16(a[mi], b[ni], acc[mi][ni], 0, 0, 0);
  }
  #pragma unroll
  for (int mi = 0; mi < 4; ++mi)
    #pragma unroll
    for (int ni = 0; ni < 2; ++ni) {
      int col = bn + ni*16 + lr;
      float bb = bias[col];
      #pragma unroll
      for (int q = 0; q < 4; ++q)
        C[(long)(bm + mi*16 + lq + q)*ldc + col] = acc[mi][ni][q] + bb;
    }
}

// same but bf16 output (for qkt)
__global__ __launch_bounds__(256) void k_gemm_bf16o(
    const unsigned short* __restrict__ A, int lda,
    const unsigned short* __restrict__ W, int ldw,
    const float* __restrict__ bias,
    unsigned short* __restrict__ C, int ldc, int K)
{
  int tid = threadIdx.x;
  int w = tid >> 6, l = tid & 63;
  int lr = l & 15, lk = (l >> 4) * 8, lq = (l >> 4) * 4;
  int bm = blockIdx.x * 64;
  int bn = blockIdx.y * 128 + w * 32;
  f32x4 acc[4][2] = {};
  for (int k0 = 0; k0 < K; k0 += 32) {
    bf16x8 a[4], b[2];
    #pragma unroll
    for (int mi = 0; mi < 4; ++mi)
      a[mi] = *(const bf16x8*)(A + (long)(bm + mi*16 + lr)*lda + k0 + lk);
    #pragma unroll
    for (int ni = 0; ni < 2; ++ni)
      b[ni] = *(const bf16x8*)(W + (long)(bn + ni*16 + lr)*ldw + k0 + lk);
    #pragma unroll
    for (int mi = 0; mi < 4; ++mi)
      #pragma unroll
      for (int ni = 0; ni < 2; ++ni)
        acc[mi][ni] = __builtin_amdgcn_mfma_f32_16x16x32_bf16(a[mi], b[ni], acc[mi][ni], 0, 0, 0);
  }
  #pragma unroll
  for (int mi = 0; mi < 4; ++mi)
    #pragma unroll
    for (int ni = 0; ni < 2; ++ni) {
      int col = bn + ni*16 + lr;
      float bb = bias[col];
      #pragma unroll
      for (int q = 0; q < 4; ++q)
        C[(long)(bm + mi*16 + lq + q)*ldc + col] = f2bf(acc[mi][ni][q] + bb);
    }
}

// ================= fused glu + residual add + layernorm ==============================
// x = res + t12[:,0:128] * sigm(t12[:,128:256]) ; LN(x) -> bf16 and/or f32; opt sum out
__global__ __launch_bounds__(256) void k_glu_addln(
    const float* __restrict__ t12, const float* __restrict__ res,
    const float* __restrict__ lg, const float* __restrict__ lb,
    float* __restrict__ sum_out, unsigned short* __restrict__ ln_bf16,
    float* __restrict__ ln_f32)
{
  int gtid = blockIdx.x*256 + threadIdx.x;
  int r = gtid >> 6;
  int l = threadIdx.x & 63;
  if (r >= B_*T_) return;
  long b4 = (long)r*256, b2 = (long)r*128;
  float xA = res[b2 + l]      + t12[b4 + l]      * sigm(t12[b4 + 128 + l]);
  float xB = res[b2 + 64 + l] + t12[b4 + 64 + l] * sigm(t12[b4 + 192 + l]);
  if (sum_out) { sum_out[b2 + l] = xA; sum_out[b2 + 64 + l] = xB; }
  float s = xA + xB, s2 = xA*xA + xB*xB;
  #pragma unroll
  for (int off = 32; off; off >>= 1) { s += __shfl_xor(s, off); s2 += __shfl_xor(s2, off); }
  float mean = s * (1.0f/128.0f);
  float var  = s2 * (1.0f/128.0f) - mean*mean;
  float inv  = rsqrtf(var + LNEPS);
  float oA = (xA - mean)*inv*lg[l]      + lb[l];
  float oB = (xB - mean)*inv*lg[64 + l] + lb[64 + l];
  if (ln_bf16) { ln_bf16[b2 + l] = f2bf(oA); ln_bf16[b2 + 64 + l] = f2bf(oB); }
  if (ln_f32)  { ln_f32[b2 + l] = oA;        ln_f32[b2 + 64 + l] = oB; }
}

// ================= temporal attention (bf16 qkt input) ===============================
__global__ __launch_bounds__(128) void k_attn_t(
    const unsigned short* __restrict__ qkt, unsigned short* __restrict__ out)
{
  int b = blockIdx.x, tid = threadIdx.x;
  __shared__ float sq[16][128], sk[16][128], sv[16][128];
  __shared__ float sc[16][4][16];
  for (int i = tid; i < T_*ENC_; i += 128) {
    int tt = i >> 7, j = i & 127;
    long a = ((long)b*T_ + tt)*384;
    sq[tt][j] = bf2f(qkt[a + j]);
    sk[tt][j] = bf2f(qkt[a + 128 + j]);
    sv[tt][j] = bf2f(qkt[a + 256 + j]);
  }
  __syncthreads();
  for (int e = tid; e < 1024; e += 128) {
    int t = e >> 6, s = (e >> 2) & 15, h2 = e & 3;
    float pp = 0.0f;
    #pragma unroll
    for (int d2 = 0; d2 < 32; ++d2) pp += sq[t][h2*32 + d2] * sk[s][h2*32 + d2];
    sc[t][h2][s] = pp * SCALE_;
  }
  __syncthreads();
  if (tid < 64) {
    int t = tid >> 2, h2 = tid & 3;
    float mx = -1e30f;
    for (int s = 0; s < 16; ++s) mx = fmaxf(mx, sc[t][h2][s]);
    float sum = 0.0f;
    for (int s = 0; s < 16; ++s) { float e2 = expf(sc[t][h2][s] - mx); sc[t][h2][s] = e2; sum += e2; }
    float inv = 1.0f / sum;
    for (int s = 0; s < 16; ++s) sc[t][h2][s] *= inv;
  }
  __syncthreads();
  int h2 = tid >> 5, d2 = tid & 31;
  for (int t = 0; t < 16; ++t) {
    float acc = 0.0f;
    for (int s = 0; s < 16; ++s) acc += sc[t][h2][s] * sv[s][h2*32 + d2];
    out[((long)b*T_ + t)*128 + tid] = f2bf(acc);
  }
}

extern "C" void kernel_launch(void* const* d_in, const int* in_sizes, int n_in,
                              void* d_out, int out_size, void* d_ws, size_t ws_size,
                              hipStream_t stream)
{
  const float* hist    = (const float*)d_in[0];
  const float* nbrs    = (const float*)d_in[1];
  const float* va      = (const float*)d_in[2];
  const float* nbrsva  = (const float*)d_in[3];
  const float* cls     = (const float*)d_in[6];
  const float* nbrscls = (const float*)d_in[7];
  const unsigned char* mask = (const unsigned char*)d_in[8];
  const float* W1  = (const float*)d_in[9];
  const float* b1  = (const float*)d_in[10];
  const float* Wih = (const float*)d_in[11];
  const float* Whh = (const float*)d_in[12];
  const float* bih = (const float*)d_in[13];
  const float* bhh = (const float*)d_in[14];
  const float* Wq  = (const float*)d_in[15];
  const float* bq  = (const float*)d_in[16];
  const float* Wk  = (const float*)d_in[17];
  const float* bk  = (const float*)d_in[18];
  const float* Wv  = (const float*)d_in[19];
  const float* bv  = (const float*)d_in[20];
  const float* Wg1a = (const float*)d_in[21];
  const float* bg1a = (const float*)d_in[22];
  const float* Wg1g = (const float*)d_in[23];
  const float* bg1g = (const float*)d_in[24];
  const float* Wqt = (const float*)d_in[25];
  const float* bqt = (const float*)d_in[26];
  const float* Wkt = (const float*)d_in[27];
  const float* bkt = (const float*)d_in[28];
  const float* Wvt = (const float*)d_in[29];
  const float* bvt = (const float*)d_in[30];
  const float* Wg2a = (const float*)d_in[31];
  const float* bg2a = (const float*)d_in[32];
  const float* Wg2g = (const float*)d_in[33];
  const float* bg2g = (const float*)d_in[34];
  const float* ln_g = (const float*)d_in[35];
  const float* ln_b = (const float*)d_in[36];

  // pick largest t-chunk the workspace affords
  size_t fixed = 0;
  {
    // everything except knvB (bytes, each rounded to 256)
    size_t items[] = {
      (size_t)GATE*KCAT*2, (size_t)GATE*4, (size_t)2*ENC_*ENC_*2, (size_t)2*ENC_*4,
      (size_t)ENC_*ENC_*2, (size_t)3*ENC_*ENC_*2, (size_t)3*ENC_*4,
      (size_t)2*ENC_*ENC_*2, (size_t)2*ENC_*4, (size_t)2*ENC_*ENC_*2, (size_t)2*ENC_*4,
      (size_t)B_*T_*ENC_*4,            // hh
      (size_t)T_*B_*ENC_*4,            // qbuf
      (size_t)MROWS*ENC_*2,            // Hsp
      (size_t)NBLK*8448*4,             // csp
      (size_t)B_*T_*ENC_*2,            // spaB
      (size_t)B_*T_*2*ENC_*4,          // t12
      (size_t)B_*T_*ENC_*4,            // S1
      (size_t)B_*T_*ENC_*2,            // valsB
      (size_t)B_*T_*3*ENC_*2,          // qktB
      (size_t)B_*T_*ENC_*2,            // atoB
      (size_t)B_*G_*4, (size_t)78*4, (size_t)4
    };
    for (size_t v : items) fixed += (v + 255) & ~(size_t)255;
  }
  int tch = 16, ltch = 4;
  while (tch > 4 && fixed + ((size_t)tch*N_*256*2 + 255) > ws_size) { tch >>= 1; ltch--; }

  char* base = (char*)d_ws;
  size_t off = 0;
  auto alloc = [&](size_t bytes) { char* r = base + off; off = (off + bytes + 255) & ~(size_t)255; return r; };
  unsigned short* WcatB = (unsigned short*)alloc(GATE*KCAT*2);
  float*          biasg = (float*)alloc(GATE*4);
  unsigned short* WkvB  = (unsigned short*)alloc(2*ENC_*ENC_*2);
  float*          bkv   = (float*)alloc(2*ENC_*4);
  unsigned short* WqB   = (unsigned short*)alloc(ENC_*ENC_*2);
  unsigned short* WqktB = (unsigned short*)alloc(3*ENC_*ENC_*2);
  float*          bqkt  = (float*)alloc(3*ENC_*4);
  unsigned short* Wg1B  = (unsigned short*)alloc(2*ENC_*ENC_*2);
  float*          bg1   = (float*)alloc(2*ENC_*4);
  unsigned short* Wg2B  = (unsigned short*)alloc(2*ENC_*ENC_*2);
  float*          bg2   = (float*)alloc(2*ENC_*4);
  float*          hh    = (float*)alloc((size_t)B_*T_*ENC_*4);
  float*          qbuf  = (float*)alloc((size_t)T_*B_*ENC_*4);
  unsigned short* Hsp   = (unsigned short*)alloc((size_t)MROWS*ENC_*2);
  float*          csp   = (float*)alloc((size_t)NBLK*8448*4);
  unsigned short* spaB  = (unsigned short*)alloc((size_t)B_*T_*ENC_*2);
  float*          t12   = (float*)alloc((size_t)B_*T_*2*ENC_*4);
  float*          S1    = (float*)alloc((size_t)B_*T_*ENC_*4);
  unsigned short* valsB = (unsigned short*)alloc((size_t)B_*T_*ENC_*2);
  unsigned short* qktB  = (unsigned short*)alloc((size_t)B_*T_*3*ENC_*2);
  unsigned short* atoB  = (unsigned short*)alloc((size_t)B_*T_*ENC_*2);
  int*            nidx  = (int*)alloc((size_t)B_*G_*4);
  int*            bcnt  = (int*)alloc(78*4);
  int*            wsel  = (int*)alloc(4);
  unsigned short* knvB  = (unsigned short*)alloc((size_t)tch*N_*256*2);

  k_prep<<<384, 256, 0, stream>>>(
      Wih, Whh, bih, bhh, Wk, bk, Wv, bv, Wq,
      Wqt, bqt, Wkt, bkt, Wvt, bvt,
      Wg1a, bg1a, Wg1g, bg1g, Wg2a, bg2a, Wg2g, bg2g,
      WcatB, biasg, WkvB, bkv, WqB, WqktB, bqkt, Wg1B, bg1, Wg2B, bg2);
  k_detect<<<1, 256, 0, stream>>>(mask, wsel);
  k_count<<<78, 256, 0, stream>>>(mask, wsel, bcnt);
  k_fill<<<78, 256, 0, stream>>>(mask, wsel, bcnt, nidx);

  AP ap;
  ap.hist = hist; ap.cls = cls; ap.va = va;
  ap.nbrs = nbrs; ap.nbrscls = nbrscls; ap.nbrsva = nbrsva;
  ap.W1 = W1; ap.b1 = b1;
  ap.Wcat = WcatB; ap.Wkv = WkvB; ap.Wq = WqB;
  ap.biasg = biasg; ap.bkv = bkv; ap.bq = bq;
  ap.hh = hh; ap.qbuf = qbuf; ap.knvB = knvB; ap.Hsp = Hsp; ap.csp = csp;
  ap.tch = tch;
  for (int c0 = 0; c0 < T_; c0 += tch) {
    ap.c0 = c0;
    k_lstm<<<NBLK, 256, 0, stream>>>(ap);
    k_attn_sp<<<(B_*tch)/4, 256, 0, stream>>>(c0, ltch, qbuf, knvB, bk, bv, nidx, spaB);
  }

  // tail
  k_gemm_bf16<<<dim3((B_*T_)/64, 2), 256, 0, stream>>>(spaB, 128, Wg1B, 128, bg1, t12, 256, 128);
  k_glu_addln<<<(B_*T_*64)/256, 256, 0, stream>>>(t12, hh, ln_g, ln_b, S1, valsB, nullptr);
  k_gemm_bf16o<<<dim3((B_*T_)/64, 3), 256, 0, stream>>>(valsB, 128, WqktB, 128, bqkt, qktB, 384, 128);
  k_attn_t<<<B_, 128, 0, stream>>>(qktB, atoB);
  k_gemm_bf16<<<dim3((B_*T_)/64, 2), 256, 0, stream>>>(atoB, 128, Wg2B, 128, bg2, t12, 256, 128);
  k_glu_addln<<<(B_*T_*64)/256, 256, 0, stream>>>(t12, S1, ln_g, ln_b, nullptr, nullptr, (float*)d_out);
}

// Round 6
// 310.637 us; speedup vs baseline: 5.1455x; 1.6544x over previous
//
#include <hip/hip_runtime.h>
#include <math.h>

#define T_ 16
#define B_ 512
#define N_ 8192
#define G_ 39
#define ENC_ 128
#define TH_ 64
#define MROWS 8704          // B_ + N_
#define GATE 512            // 4*ENC_
#define KCAT 192            // TH_ + ENC_
#define SCALE_ 0.08838834764831845f
#define LNEPS 1e-5f
#define NBLK 136            // MROWS/64

typedef short bf16x8 __attribute__((ext_vector_type(8)));
typedef float f32x4  __attribute__((ext_vector_type(4)));

__device__ __forceinline__ float sigm(float x){ return 1.0f/(1.0f+expf(-x)); }
__device__ __forceinline__ float rcpf(float x){ return __builtin_amdgcn_rcpf(x); }
__device__ __forceinline__ float sigm_f(float x){ return rcpf(1.0f + __expf(-x)); }
__device__ __forceinline__ float tanh_f(float x){ return 1.0f - 2.0f*rcpf(__expf(2.0f*x) + 1.0f); }
__device__ __forceinline__ unsigned short f2bf(float f){
  unsigned int u = __float_as_uint(f);
  unsigned int r = u + 0x7FFFu + ((u>>16)&1u);
  return (unsigned short)(r>>16);
}
__device__ __forceinline__ float bf2f(unsigned short h){
  return __uint_as_float(((unsigned int)h)<<16);
}

// ================= prep: convert weights to bf16, build fused biases =================
__global__ __launch_bounds__(256) void k_prep(
    const float* __restrict__ Wih, const float* __restrict__ Whh,
    const float* __restrict__ bih, const float* __restrict__ bhh,
    const float* __restrict__ Wk,  const float* __restrict__ bk,
    const float* __restrict__ Wv,  const float* __restrict__ bv,
    const float* __restrict__ Wq,
    const float* __restrict__ Wqt, const float* __restrict__ bqt,
    const float* __restrict__ Wkt, const float* __restrict__ bkt,
    const float* __restrict__ Wvt, const float* __restrict__ bvt,
    const float* __restrict__ Wg1a, const float* __restrict__ bg1a,
    const float* __restrict__ Wg1g, const float* __restrict__ bg1g,
    const float* __restrict__ Wg2a, const float* __restrict__ bg2a,
    const float* __restrict__ Wg2g, const float* __restrict__ bg2g,
    unsigned short* __restrict__ WcatB, float* __restrict__ biasg,
    unsigned short* __restrict__ WkvB,  float* __restrict__ bkv,
    unsigned short* __restrict__ WqB,
    unsigned short* __restrict__ WqktB, float* __restrict__ bqkt,
    unsigned short* __restrict__ Wg1B,  float* __restrict__ bg1,
    unsigned short* __restrict__ Wg2B,  float* __restrict__ bg2)
{
  int i = blockIdx.x*256 + threadIdx.x;
  if (i < GATE*KCAT) {
    int n = i / KCAT, k = i % KCAT;
    WcatB[i] = f2bf((k < TH_) ? Wih[n*TH_ + k] : Whh[n*ENC_ + (k - TH_)]);
  }
  if (i < GATE) biasg[i] = bih[i] + bhh[i];
  if (i < 2*ENC_*ENC_) {
    int n = i >> 7, k = i & 127;
    WkvB[i] = f2bf((n < ENC_) ? Wk[n*ENC_ + k] : Wv[(n-ENC_)*ENC_ + k]);
    Wg1B[i] = f2bf((n < ENC_) ? Wg1a[n*ENC_ + k] : Wg1g[(n-ENC_)*ENC_ + k]);
    Wg2B[i] = f2bf((n < ENC_) ? Wg2a[n*ENC_ + k] : Wg2g[(n-ENC_)*ENC_ + k]);
  }
  if (i < 2*ENC_) {
    bkv[i] = (i < ENC_) ? bk[i] : bv[i-ENC_];
    bg1[i] = (i < ENC_) ? bg1a[i] : bg1g[i-ENC_];
    bg2[i] = (i < ENC_) ? bg2a[i] : bg2g[i-ENC_];
  }
  if (i < ENC_*ENC_) WqB[i] = f2bf(Wq[i]);
  if (i < 3*ENC_*ENC_) {
    int n = i >> 7, k = i & 127;
    float w = (n < ENC_) ? Wqt[n*ENC_ + k] : (n < 2*ENC_) ? Wkt[(n-ENC_)*ENC_ + k]
                                                          : Wvt[(n-2*ENC_)*ENC_ + k];
    WqktB[i] = f2bf(w);
  }
  if (i < 3*ENC_) bqkt[i] = (i < ENC_) ? bqt[i] : (i < 2*ENC_) ? bkt[i-ENC_] : bvt[i-2*ENC_];
}

// ================= mask width detect / count / fill (proven) =========================
__device__ __forceinline__ int cellval(const unsigned char* m, long cell, int w) {
  long byte = cell * 128L * w;
  if (w == 1) return m[byte] != 0;
  if (w == 2) return *(const unsigned short*)(m + byte) != 0;
  if (w == 4) return *(const unsigned int*)(m + byte) != 0;
  return *(const unsigned long long*)(m + byte) != 0ULL;
}
__device__ __forceinline__ int cellconsist(const unsigned char* m, long cell, int w) {
  long byte = cell * 128L * w;
  if (w == 1) { unsigned char v = m[byte];
    for (int j = 1; j < 8; ++j) if (m[byte + j] != v) return 0; return 1; }
  if (w == 2) { unsigned short v = *(const unsigned short*)(m + byte);
    for (int j = 1; j < 8; ++j) if (*(const unsigned short*)(m + byte + 2L*j) != v) return 0; return 1; }
  if (w == 4) { unsigned int v = *(const unsigned int*)(m + byte);
    for (int j = 1; j < 8; ++j) if (*(const unsigned int*)(m + byte + 4L*j) != v) return 0; return 1; }
  unsigned long long v = *(const unsigned long long*)(m + byte);
  for (int j = 1; j < 8; ++j) if (*(const unsigned long long*)(m + byte + 8L*j) != v) return 0; return 1;
}

__global__ void k_detect(const unsigned char* __restrict__ mask, int* __restrict__ wsel)
{
  __shared__ int bad;
  int tid = threadIdx.x;
  int chosen = 0;
  for (int w = 1; w <= 8 && !chosen; w <<= 1) {
    if (tid == 0) bad = 0;
    __syncthreads();
    int ok = 1;
    for (int c = tid; c < 512; c += 256) ok &= cellconsist(mask, c, w);
    if (!ok) bad = 1;
    __syncthreads();
    if (!bad) chosen = w;
    __syncthreads();
  }
  if (tid == 0) *wsel = chosen ? chosen : 1;
}

__global__ void k_count(const unsigned char* __restrict__ mask,
                        const int* __restrict__ wsel, int* __restrict__ bcnt)
{
  __shared__ int sc[256];
  int tid = threadIdx.x;
  long cell = (long)blockIdx.x*256 + tid;
  sc[tid] = cellval(mask, cell, *wsel);
  __syncthreads();
  for (int off = 128; off; off >>= 1) {
    if (tid < off) sc[tid] += sc[tid + off];
    __syncthreads();
  }
  if (tid == 0) bcnt[blockIdx.x] = sc[0];
}

__global__ void k_fill(const unsigned char* __restrict__ mask,
                       const int* __restrict__ wsel, const int* __restrict__ bcnt,
                       int* __restrict__ nidx)
{
  __shared__ int sc[256];
  int tid = threadIdx.x, blk = blockIdx.x;
  long cell = (long)blk*256 + tid;
  int on = cellval(mask, cell, *wsel);
  sc[tid] = on;
  __syncthreads();
  for (int off = 1; off < 256; off <<= 1) {
    int v = (tid >= off) ? sc[tid - off] : 0;
    __syncthreads();
    sc[tid] += v;
    __syncthreads();
  }
  int base = 0;
  for (int i = 0; i < blk; ++i) base += bcnt[i];
  nidx[cell] = on ? (base + sc[tid] - 1) : -1;
}

// ================= kernel A: fused encode + LSTM chunk + kv/q projections ============
struct AP {
  const float *hist, *cls, *va, *nbrs, *nbrscls, *nbrsva;
  const float *W1, *b1;
  const unsigned short *Wcat, *Wkv, *Wq;
  const float *biasg, *bkv, *bq;
  float *hh;                 // (B,T,128) f32
  float *qbuf;               // (T,B,128) f32
  unsigned short *knvB;      // (tch,N,256) bf16
  unsigned short *Hsp;       // (MROWS,128) bf16 spill (swizzled content)
  float *csp;                // (NBLK*512*16) f32 spill of c-registers
  int c0, tch;
};

// 512 threads = 8 waves; each wave owns 16 gate-channels (x4 gates) for 64 rows.
// Gate weights live in registers for the whole chunk; c-state lives in registers.
__global__ __launch_bounds__(512, 2) void k_lstm(AP p)
{
  __shared__ unsigned short Hl[2*64*128];   // H double-buffer, XOR-swizzled
  __shared__ unsigned short Xl[64*64];      // encoded inputs, XOR-swizzled
  __shared__ float finl[16][64][5];         // all-chunk raw features

  const int tid = threadIdx.x;
  const int w = tid >> 6, l = tid & 63;
  const int lr = l & 15, lk = (l >> 4) * 8, lq = (l >> 4) * 4;
  const int bi = blockIdx.x, bm = bi * 64;
  const bool ish = (bi < 8);

  // ---- preload gate weights into registers: 4 gates x 6 k-steps ----
  bf16x8 wg[4][6];
  #pragma unroll
  for (int g = 0; g < 4; ++g)
    #pragma unroll
    for (int ks = 0; ks < 6; ++ks)
      wg[g][ks] = *(const bf16x8*)(p.Wcat + (long)(g*128 + w*16 + lr)*KCAT + ks*32 + lk);

  const int ch = w*16 + lr;
  const float bgi = p.biasg[ch], bgf = p.biasg[128+ch],
              bgg = p.biasg[256+ch], bgo = p.biasg[384+ch];

  // ---- W1 row for encode (column l) ----
  const float w1c0 = p.W1[l*5+0], w1c1 = p.W1[l*5+1], w1c2 = p.W1[l*5+2],
              w1c3 = p.W1[l*5+3], w1c4 = p.W1[l*5+4], b1c = p.b1[l];

  // ---- stage all raw features for this chunk into LDS ----
  for (int idx = tid; idx < p.tch*320; idx += 512) {
    int t4 = idx / 320, rem = idx - t4*320;
    int row = rem / 5, f = rem - row*5;
    long r = ish ? ((long)(p.c0 + t4)*B_ + bm + row) : ((long)(p.c0 + t4)*N_ + (bm - B_) + row);
    const float* ph = ish ? p.hist : p.nbrs;
    const float* pc = ish ? p.cls  : p.nbrscls;
    const float* pv = ish ? p.va   : p.nbrsva;
    finl[t4][row][f] = (f < 2) ? ph[r*2 + f] : (f == 2) ? pc[r] : pv[r*2 + (f-3)];
  }

  // ---- restore / init state ----
  float creg[4][4];
  if (p.c0 == 0) {
    for (int i = tid; i < 64*128; i += 512) Hl[i] = 0;
    #pragma unroll
    for (int mi = 0; mi < 4; ++mi)
      #pragma unroll
      for (int q = 0; q < 4; ++q) creg[mi][q] = 0.0f;
  } else {
    for (int i = tid; i < 64*128; i += 512) Hl[i] = p.Hsp[(long)bm*128 + i];
    #pragma unroll
    for (int mi = 0; mi < 4; ++mi)
      #pragma unroll
      for (int q = 0; q < 4; ++q) creg[mi][q] = p.csp[((long)bi*512 + tid)*16 + mi*4 + q];
  }
  __syncthreads();

  int cur = 0;
  for (int tl = 0; tl < p.tch; ++tl) {
    int t = p.c0 + tl;
    // ---- encode: elu(features . W1[l]) -> Xl (swizzled); 8 rows per thread ----
    {
      #pragma unroll
      for (int j = 0; j < 8; ++j) {
        int row = w*8 + j;
        float s = b1c + finl[tl][row][0]*w1c0 + finl[tl][row][1]*w1c1
                      + finl[tl][row][2]*w1c2 + finl[tl][row][3]*w1c3
                      + finl[tl][row][4]*w1c4;
        s = (s > 0.0f) ? s : expm1f(s);
        Xl[row*64 + (l ^ ((row & 7) << 3))] = f2bf(s);
      }
    }
    __syncthreads();
    // ---- gate GEMM: regs(B) x LDS(A); 96 MFMA ----
    f32x4 acc[4][4] = {};     // [gate][mi]
    #pragma unroll
    for (int ks = 0; ks < 2; ++ks) {          // K 0..63 from Xl
      bf16x8 a[4];
      #pragma unroll
      for (int mi = 0; mi < 4; ++mi) {
        int row = mi*16 + lr;
        int col = (ks*32 + lk) ^ ((row & 7) << 3);
        a[mi] = *(const bf16x8*)(Xl + row*64 + col);
      }
      #pragma unroll
      for (int g = 0; g < 4; ++g)
        #pragma unroll
        for (int mi = 0; mi < 4; ++mi)
          acc[g][mi] = __builtin_amdgcn_mfma_f32_16x16x32_bf16(a[mi], wg[g][ks], acc[g][mi], 0, 0, 0);
    }
    #pragma unroll
    for (int ks = 0; ks < 4; ++ks) {          // K 64..191 from Hl[cur]
      bf16x8 a[4];
      #pragma unroll
      for (int mi = 0; mi < 4; ++mi) {
        int row = mi*16 + lr;
        int col = (ks*32 + lk) ^ ((row & 7) << 3);
        a[mi] = *(const bf16x8*)(Hl + cur*8192 + row*128 + col);
      }
      #pragma unroll
      for (int g = 0; g < 4; ++g)
        #pragma unroll
        for (int mi = 0; mi < 4; ++mi)
          acc[g][mi] = __builtin_amdgcn_mfma_f32_16x16x32_bf16(a[mi], wg[g][2+ks], acc[g][mi], 0, 0, 0);
    }
    // ---- lane-local cell update (c in registers) ----
    int nxt = cur ^ 1;
    #pragma unroll
    for (int mi = 0; mi < 4; ++mi)
      #pragma unroll
      for (int q = 0; q < 4; ++q) {
        int row = mi*16 + lq + q;
        float gi = acc[0][mi][q] + bgi;
        float gf = acc[1][mi][q] + bgf;
        float gg = acc[2][mi][q] + bgg;
        float go = acc[3][mi][q] + bgo;
        float cc = sigm_f(gf)*creg[mi][q] + sigm_f(gi)*tanh_f(gg);
        creg[mi][q] = cc;
        float hv = sigm_f(go)*tanh_f(cc);
        Hl[nxt*8192 + row*128 + (ch ^ ((row & 7) << 3))] = f2bf(hv);
        if (ish) p.hh[((long)(bm + row)*T_ + t)*128 + ch] = hv;
      }
    __syncthreads();
    cur = nxt;
    // ---- projections from new H: kv (nbr blocks) / q (hist blocks) ----
    if (!ish) {
      f32x4 a2[4][2] = {};
      #pragma unroll
      for (int ks = 0; ks < 4; ++ks) {
        bf16x8 a[4];
        #pragma unroll
        for (int mi = 0; mi < 4; ++mi) {
          int row = mi*16 + lr;
          int col = (ks*32 + lk) ^ ((row & 7) << 3);
          a[mi] = *(const bf16x8*)(Hl + cur*8192 + row*128 + col);
        }
        #pragma unroll
        for (int ni = 0; ni < 2; ++ni) {
          bf16x8 b = *(const bf16x8*)(p.Wkv + (long)(w*32 + ni*16 + lr)*128 + ks*32 + lk);
          #pragma unroll
          for (int mi = 0; mi < 4; ++mi)
            a2[mi][ni] = __builtin_amdgcn_mfma_f32_16x16x32_bf16(a[mi], b, a2[mi][ni], 0, 0, 0);
        }
      }
      long nr = bm - B_;
      #pragma unroll
      for (int mi = 0; mi < 4; ++mi)
        #pragma unroll
        for (int ni = 0; ni < 2; ++ni) {
          int c2 = w*32 + ni*16 + lr;
          float bb = p.bkv[c2];
          #pragma unroll
          for (int q = 0; q < 4; ++q)
            p.knvB[((long)tl*N_ + nr + mi*16 + lq + q)*256 + c2] = f2bf(a2[mi][ni][q] + bb);
        }
    } else {
      f32x4 a2[4] = {};
      #pragma unroll
      for (int ks = 0; ks < 4; ++ks) {
        bf16x8 a[4];
        #pragma unroll
        for (int mi = 0; mi < 4; ++mi) {
          int row = mi*16 + lr;
          int col = (ks*32 + lk) ^ ((row & 7) << 3);
          a[mi] = *(const bf16x8*)(Hl + cur*8192 + row*128 + col);
        }
        bf16x8 b = *(const bf16x8*)(p.Wq + (long)(w*16 + lr)*128 + ks*32 + lk);
        #pragma unroll
        for (int mi = 0; mi < 4; ++mi)
          a2[mi] = __builtin_amdgcn_mfma_f32_16x16x32_bf16(a[mi], b, a2[mi], 0, 0, 0);
      }
      float bb = p.bq[ch];
      #pragma unroll
      for (int mi = 0; mi < 4; ++mi)
        #pragma unroll
        for (int q = 0; q < 4; ++q)
          p.qbuf[((long)t*B_ + bm + mi*16 + lq + q)*128 + ch] = a2[mi][q] + bb;
    }
    __syncthreads();
  }
  // ---- spill state for next chunk ----
  for (int i = tid; i < 64*128; i += 512) p.Hsp[(long)bm*128 + i] = Hl[cur*8192 + i];
  #pragma unroll
  for (int mi = 0; mi < 4; ++mi)
    #pragma unroll
    for (int q = 0; q < 4; ++q)
      p.csp[((long)bi*512 + tid)*16 + mi*4 + q] = creg[mi][q];
}

// ================= kernel B: spatial attention, one wave per (b, t) ==================
__global__ __launch_bounds__(256) void k_attn_sp(
    int c0, int ltch,
    const float* __restrict__ qbuf, const unsigned short* __restrict__ knvB,
    const float* __restrict__ bk, const float* __restrict__ bv,
    const int* __restrict__ nidx, unsigned short* __restrict__ spaB)
{
  int tid = threadIdx.x;
  int w = tid >> 6, l = tid & 63;
  __shared__ int sn[4][G_];
  __shared__ float aw[4][4][40];
  int gwid = blockIdx.x*4 + w;
  int b = gwid >> ltch;
  int tl = gwid & ((1 << ltch) - 1);
  int t = c0 + tl;
  if (l < G_) sn[w][l] = nidx[b*G_ + l];
  __syncthreads();
  float qA = qbuf[((long)t*B_ + b)*128 + l];
  float qB = qbuf[((long)t*B_ + b)*128 + 64 + l];
  for (int g = 0; g < G_; ++g) {
    int ni = sn[w][g];
    const unsigned short* kr = knvB + ((long)tl*N_ + ni)*256;
    float kA = (ni >= 0) ? bf2f(kr[l])      : bk[l];
    float kB = (ni >= 0) ? bf2f(kr[64 + l]) : bk[64 + l];
    float pA = qA*kA, pB = qB*kB;
    pA += __shfl_xor(pA, 16); pA += __shfl_xor(pA, 8); pA += __shfl_xor(pA, 4);
    pA += __shfl_xor(pA, 2);  pA += __shfl_xor(pA, 1);
    pB += __shfl_xor(pB, 16); pB += __shfl_xor(pB, 8); pB += __shfl_xor(pB, 4);
    pB += __shfl_xor(pB, 2);  pB += __shfl_xor(pB, 1);
    if ((l & 31) == 0) {
      int hb = l >> 5;
      aw[w][hb][g]     = pA * SCALE_;
      aw[w][2+hb][g]   = pB * SCALE_;
    }
  }
  __syncthreads();
  int hA = l >> 5, hB = 2 + (l >> 5);
  float mxA = -1e30f, mxB = -1e30f;
  for (int g = 0; g < G_; ++g) {
    mxA = fmaxf(mxA, aw[w][hA][g]);
    mxB = fmaxf(mxB, aw[w][hB][g]);
  }
  float sA = 0.f, sB = 0.f, oA = 0.f, oB = 0.f;
  for (int g = 0; g < G_; ++g) {
    int ni = sn[w][g];
    const unsigned short* vr = knvB + ((long)tl*N_ + ni)*256 + 128;
    float vA = (ni >= 0) ? bf2f(vr[l])      : bv[l];
    float vB = (ni >= 0) ? bf2f(vr[64 + l]) : bv[64 + l];
    float eA = expf(aw[w][hA][g] - mxA);
    float eB = expf(aw[w][hB][g] - mxB);
    sA += eA; sB += eB; oA += eA*vA; oB += eB*vB;
  }
  spaB[((long)b*T_ + t)*128 + l]      = f2bf(oA / sA);
  spaB[((long)b*T_ + t)*128 + 64 + l] = f2bf(oB / sB);
}

// ================= bf16 MFMA GEMM: C f32 out =========================================
__global__ __launch_bounds__(256) void k_gemm_bf16(
    const unsigned short* __restrict__ A, int lda,
    const unsigned short* __restrict__ W, int ldw,
    const float* __restrict__ bias,
    float* __restrict__ C, int ldc, int K)
{
  int tid = threadIdx.x;
  int w = tid >> 6, l = tid & 63;
  int lr = l & 15, lk = (l >> 4) * 8, lq = (l >> 4) * 4;
  int bm = blockIdx.x * 64;
  int bn = blockIdx.y * 128 + w * 32;
  f32x4 acc[4][2] = {};
  for (int k0 = 0; k0 < K; k0 += 32) {
    bf16x8 a[4], b[2];
    #pragma unroll
    for (int mi = 0; mi < 4; ++mi)
      a[mi] = *(const bf16x8*)(A + (long)(bm + mi*16 + lr)*lda + k0 + lk);
    #pragma unroll
    for (int ni = 0; ni < 2; ++ni)
      b[ni] = *(const bf16x8*)(W + (long)(bn + ni*16 + lr)*ldw + k0 + lk);
    #pragma unroll
    for (int mi = 0; mi < 4; ++mi)
      #pragma unroll
      for (int ni = 0; ni < 2; ++ni)
        acc[mi][ni] = __builtin_amdgcn_mfma_f32_16x16x32_bf16(a[mi], b[ni], acc[mi][ni], 0, 0, 0);
  }
  #pragma unroll
  for (int mi = 0; mi < 4; ++mi)
    #pragma unroll
    for (int ni = 0; ni < 2; ++ni) {
      int col = bn + ni*16 + lr;
      float bb = bias[col];
      #pragma unroll
      for (int q = 0; q < 4; ++q)
        C[(long)(bm + mi*16 + lq + q)*ldc + col] = acc[mi][ni][q] + bb;
    }
}

// same but bf16 output (for qkt)
__global__ __launch_bounds__(256) void k_gemm_bf16o(
    const unsigned short* __restrict__ A, int lda,
    const unsigned short* __restrict__ W, int ldw,
    const float* __restrict__ bias,
    unsigned short* __restrict__ C, int ldc, int K)
{
  int tid = threadIdx.x;
  int w = tid >> 6, l = tid & 63;
  int lr = l & 15, lk = (l >> 4) * 8, lq = (l >> 4) * 4;
  int bm = blockIdx.x * 64;
  int bn = blockIdx.y * 128 + w * 32;
  f32x4 acc[4][2] = {};
  for (int k0 = 0; k0 < K; k0 += 32) {
    bf16x8 a[4], b[2];
    #pragma unroll
    for (int mi = 0; mi < 4; ++mi)
      a[mi] = *(const bf16x8*)(A + (long)(bm + mi*16 + lr)*lda + k0 + lk);
    #pragma unroll
    for (int ni = 0; ni < 2; ++ni)
      b[ni] = *(const bf16x8*)(W + (long)(bn + ni*16 + lr)*ldw + k0 + lk);
    #pragma unroll
    for (int mi = 0; mi < 4; ++mi)
      #pragma unroll
      for (int ni = 0; ni < 2; ++ni)
        acc[mi][ni] = __builtin_amdgcn_mfma_f32_16x16x32_bf16(a[mi], b[ni], acc[mi][ni], 0, 0, 0);
  }
  #pragma unroll
  for (int mi = 0; mi < 4; ++mi)
    #pragma unroll
    for (int ni = 0; ni < 2; ++ni) {
      int col = bn + ni*16 + lr;
      float bb = bias[col];
      #pragma unroll
      for (int q = 0; q < 4; ++q)
        C[(long)(bm + mi*16 + lq + q)*ldc + col] = f2bf(acc[mi][ni][q] + bb);
    }
}

// ================= fused glu + residual add + layernorm ==============================
__global__ __launch_bounds__(256) void k_glu_addln(
    const float* __restrict__ t12, const float* __restrict__ res,
    const float* __restrict__ lg, const float* __restrict__ lb,
    float* __restrict__ sum_out, unsigned short* __restrict__ ln_bf16,
    float* __restrict__ ln_f32)
{
  int gtid = blockIdx.x*256 + threadIdx.x;
  int r = gtid >> 6;
  int l = threadIdx.x & 63;
  if (r >= B_*T_) return;
  long b4 = (long)r*256, b2 = (long)r*128;
  float xA = res[b2 + l]      + t12[b4 + l]      * sigm(t12[b4 + 128 + l]);
  float xB = res[b2 + 64 + l] + t12[b4 + 64 + l] * sigm(t12[b4 + 192 + l]);
  if (sum_out) { sum_out[b2 + l] = xA; sum_out[b2 + 64 + l] = xB; }
  float s = xA + xB, s2 = xA*xA + xB*xB;
  #pragma unroll
  for (int off = 32; off; off >>= 1) { s += __shfl_xor(s, off); s2 += __shfl_xor(s2, off); }
  float mean = s * (1.0f/128.0f);
  float var  = s2 * (1.0f/128.0f) - mean*mean;
  float inv  = rsqrtf(var + LNEPS);
  float oA = (xA - mean)*inv*lg[l]      + lb[l];
  float oB = (xB - mean)*inv*lg[64 + l] + lb[64 + l];
  if (ln_bf16) { ln_bf16[b2 + l] = f2bf(oA); ln_bf16[b2 + 64 + l] = f2bf(oB); }
  if (ln_f32)  { ln_f32[b2 + l] = oA;        ln_f32[b2 + 64 + l] = oB; }
}

// ================= temporal attention (bf16 qkt input) ===============================
__global__ __launch_bounds__(128) void k_attn_t(
    const unsigned short* __restrict__ qkt, unsigned short* __restrict__ out)
{
  int b = blockIdx.x, tid = threadIdx.x;
  __shared__ float sq[16][128], sk[16][128], sv[16][128];
  __shared__ float sc[16][4][16];
  for (int i = tid; i < T_*ENC_; i += 128) {
    int tt = i >> 7, j = i & 127;
    long a = ((long)b*T_ + tt)*384;
    sq[tt][j] = bf2f(qkt[a + j]);
    sk[tt][j] = bf2f(qkt[a + 128 + j]);
    sv[tt][j] = bf2f(qkt[a + 256 + j]);
  }
  __syncthreads();
  for (int e = tid; e < 1024; e += 128) {
    int t = e >> 6, s = (e >> 2) & 15, h2 = e & 3;
    float pp = 0.0f;
    #pragma unroll
    for (int d2 = 0; d2 < 32; ++d2) pp += sq[t][h2*32 + d2] * sk[s][h2*32 + d2];
    sc[t][h2][s] = pp * SCALE_;
  }
  __syncthreads();
  if (tid < 64) {
    int t = tid >> 2, h2 = tid & 3;
    float mx = -1e30f;
    for (int s = 0; s < 16; ++s) mx = fmaxf(mx, sc[t][h2][s]);
    float sum = 0.0f;
    for (int s = 0; s < 16; ++s) { float e2 = expf(sc[t][h2][s] - mx); sc[t][h2][s] = e2; sum += e2; }
    float inv = 1.0f / sum;
    for (int s = 0; s < 16; ++s) sc[t][h2][s] *= inv;
  }
  __syncthreads();
  int h2 = tid >> 5, d2 = tid & 31;
  for (int t = 0; t < 16; ++t) {
    float acc = 0.0f;
    for (int s = 0; s < 16; ++s) acc += sc[t][h2][s] * sv[s][h2*32 + d2];
    out[((long)b*T_ + t)*128 + tid] = f2bf(acc);
  }
}

extern "C" void kernel_launch(void* const* d_in, const int* in_sizes, int n_in,
                              void* d_out, int out_size, void* d_ws, size_t ws_size,
                              hipStream_t stream)
{
  const float* hist    = (const float*)d_in[0];
  const float* nbrs    = (const float*)d_in[1];
  const float* va      = (const float*)d_in[2];
  const float* nbrsva  = (const float*)d_in[3];
  const float* cls     = (const float*)d_in[6];
  const float* nbrscls = (const float*)d_in[7];
  const unsigned char* mask = (const unsigned char*)d_in[8];
  const float* W1  = (const float*)d_in[9];
  const float* b1  = (const float*)d_in[10];
  const float* Wih = (const float*)d_in[11];
  const float* Whh = (const float*)d_in[12];
  const float* bih = (const float*)d_in[13];
  const float* bhh = (const float*)d_in[14];
  const float* Wq  = (const float*)d_in[15];
  const float* bq  = (const float*)d_in[16];
  const float* Wk  = (const float*)d_in[17];
  const float* bk  = (const float*)d_in[18];
  const float* Wv  = (const float*)d_in[19];
  const float* bv  = (const float*)d_in[20];
  const float* Wg1a = (const float*)d_in[21];
  const float* bg1a = (const float*)d_in[22];
  const float* Wg1g = (const float*)d_in[23];
  const float* bg1g = (const float*)d_in[24];
  const float* Wqt = (const float*)d_in[25];
  const float* bqt = (const float*)d_in[26];
  const float* Wkt = (const float*)d_in[27];
  const float* bkt = (const float*)d_in[28];
  const float* Wvt = (const float*)d_in[29];
  const float* bvt = (const float*)d_in[30];
  const float* Wg2a = (const float*)d_in[31];
  const float* bg2a = (const float*)d_in[32];
  const float* Wg2g = (const float*)d_in[33];
  const float* bg2g = (const float*)d_in[34];
  const float* ln_g = (const float*)d_in[35];
  const float* ln_b = (const float*)d_in[36];

  // pick largest t-chunk the workspace affords
  size_t fixed = 0;
  {
    size_t items[] = {
      (size_t)GATE*KCAT*2, (size_t)GATE*4, (size_t)2*ENC_*ENC_*2, (size_t)2*ENC_*4,
      (size_t)ENC_*ENC_*2, (size_t)3*ENC_*ENC_*2, (size_t)3*ENC_*4,
      (size_t)2*ENC_*ENC_*2, (size_t)2*ENC_*4, (size_t)2*ENC_*ENC_*2, (size_t)2*ENC_*4,
      (size_t)B_*T_*ENC_*4,            // hh
      (size_t)T_*B_*ENC_*4,            // qbuf
      (size_t)MROWS*ENC_*2,            // Hsp
      (size_t)NBLK*512*16*4,           // csp
      (size_t)B_*T_*ENC_*2,            // spaB
      (size_t)B_*T_*2*ENC_*4,          // t12
      (size_t)B_*T_*ENC_*4,            // S1
      (size_t)B_*T_*ENC_*2,            // valsB
      (size_t)B_*T_*3*ENC_*2,          // qktB
      (size_t)B_*T_*ENC_*2,            // atoB
      (size_t)B_*G_*4, (size_t)78*4, (size_t)4
    };
    for (size_t v : items) fixed += (v + 255) & ~(size_t)255;
  }
  int tch = 16, ltch = 4;
  while (tch > 4 && fixed + ((size_t)tch*N_*256*2 + 255) > ws_size) { tch >>= 1; ltch--; }

  char* base = (char*)d_ws;
  size_t off = 0;
  auto alloc = [&](size_t bytes) { char* r = base + off; off = (off + bytes + 255) & ~(size_t)255; return r; };
  unsigned short* WcatB = (unsigned short*)alloc(GATE*KCAT*2);
  float*          biasg = (float*)alloc(GATE*4);
  unsigned short* WkvB  = (unsigned short*)alloc(2*ENC_*ENC_*2);
  float*          bkv   = (float*)alloc(2*ENC_*4);
  unsigned short* WqB   = (unsigned short*)alloc(ENC_*ENC_*2);
  unsigned short* WqktB = (unsigned short*)alloc(3*ENC_*ENC_*2);
  float*          bqkt  = (float*)alloc(3*ENC_*4);
  unsigned short* Wg1B  = (unsigned short*)alloc(2*ENC_*ENC_*2);
  float*          bg1   = (float*)alloc(2*ENC_*4);
  unsigned short* Wg2B  = (unsigned short*)alloc(2*ENC_*ENC_*2);
  float*          bg2   = (float*)alloc(2*ENC_*4);
  float*          hh    = (float*)alloc((size_t)B_*T_*ENC_*4);
  float*          qbuf  = (float*)alloc((size_t)T_*B_*ENC_*4);
  unsigned short* Hsp   = (unsigned short*)alloc((size_t)MROWS*ENC_*2);
  float*          csp   = (float*)alloc((size_t)NBLK*512*16*4);
  unsigned short* spaB  = (unsigned short*)alloc((size_t)B_*T_*ENC_*2);
  float*          t12   = (float*)alloc((size_t)B_*T_*2*ENC_*4);
  float*          S1    = (float*)alloc((size_t)B_*T_*ENC_*4);
  unsigned short* valsB = (unsigned short*)alloc((size_t)B_*T_*ENC_*2);
  unsigned short* qktB  = (unsigned short*)alloc((size_t)B_*T_*3*ENC_*2);
  unsigned short* atoB  = (unsigned short*)alloc((size_t)B_*T_*ENC_*2);
  int*            nidx  = (int*)alloc((size_t)B_*G_*4);
  int*            bcnt  = (int*)alloc(78*4);
  int*            wsel  = (int*)alloc(4);
  unsigned short* knvB  = (unsigned short*)alloc((size_t)tch*N_*256*2);

  k_prep<<<384, 256, 0, stream>>>(
      Wih, Whh, bih, bhh, Wk, bk, Wv, bv, Wq,
      Wqt, bqt, Wkt, bkt, Wvt, bvt,
      Wg1a, bg1a, Wg1g, bg1g, Wg2a, bg2a, Wg2g, bg2g,
      WcatB, biasg, WkvB, bkv, WqB, WqktB, bqkt, Wg1B, bg1, Wg2B, bg2);
  k_detect<<<1, 256, 0, stream>>>(mask, wsel);
  k_count<<<78, 256, 0, stream>>>(mask, wsel, bcnt);
  k_fill<<<78, 256, 0, stream>>>(mask, wsel, bcnt, nidx);

  AP ap;
  ap.hist = hist; ap.cls = cls; ap.va = va;
  ap.nbrs = nbrs; ap.nbrscls = nbrscls; ap.nbrsva = nbrsva;
  ap.W1 = W1; ap.b1 = b1;
  ap.Wcat = WcatB; ap.Wkv = WkvB; ap.Wq = WqB;
  ap.biasg = biasg; ap.bkv = bkv; ap.bq = bq;
  ap.hh = hh; ap.qbuf = qbuf; ap.knvB = knvB; ap.Hsp = Hsp; ap.csp = csp;
  ap.tch = tch;
  for (int c0 = 0; c0 < T_; c0 += tch) {
    ap.c0 = c0;
    k_lstm<<<NBLK, 512, 0, stream>>>(ap);
    k_attn_sp<<<(B_*tch)/4, 256, 0, stream>>>(c0, ltch, qbuf, knvB, bk, bv, nidx, spaB);
  }

  // tail
  k_gemm_bf16<<<dim3((B_*T_)/64, 2), 256, 0, stream>>>(spaB, 128, Wg1B, 128, bg1, t12, 256, 128);
  k_glu_addln<<<(B_*T_*64)/256, 256, 0, stream>>>(t12, hh, ln_g, ln_b, S1, valsB, nullptr);
  k_gemm_bf16o<<<dim3((B_*T_)/64, 3), 256, 0, stream>>>(valsB, 128, WqktB, 128, bqkt, qktB, 384, 128);
  k_attn_t<<<B_, 128, 0, stream>>>(qktB, atoB);
  k_gemm_bf16<<<dim3((B_*T_)/64, 2), 256, 0, stream>>>(atoB, 128, Wg2B, 128, bg2, t12, 256, 128);
  k_glu_addln<<<(B_*T_*64)/256, 256, 0, stream>>>(t12, S1, ln_g, ln_b, nullptr, nullptr, (float*)d_out);
}